// Round 6
// baseline (637.031 us; speedup 1.0000x reference)
//
#include <hip/hip_runtime.h>
#include <hip/hip_bf16.h>
#include <math.h>

#define N_USERS_C 100000
#define BK_SHIFT 9
#define BK_NODES 512

__device__ __forceinline__ unsigned int pack_bf16(float a, float b) {
    __hip_bfloat16 ha = __float2bfloat16(a), hb = __float2bfloat16(b);
    return ((unsigned int)(*(unsigned short*)&hb) << 16) | (unsigned int)(*(unsigned short*)&ha);
}

// ---------------- small helpers ----------------
__global__ void k_zero_i(int* __restrict__ p, int n) {
    int i = blockIdx.x * 256 + threadIdx.x;
    if (i < n) p[i] = 0;
}

// x (f32) -> packed bf16x2 (RNE)
__global__ void k_tobf16(const float* __restrict__ x, unsigned int* __restrict__ xb, int n2) {
    int i = blockIdx.x * 256 + threadIdx.x;
    if (i >= n2) return;
    float2 v = ((const float2*)x)[i];
    xb[i] = pack_bf16(v.x, v.y);
}

// ---------------- pass 0: coarse histogram over buckets ----------------
__global__ __launch_bounds__(512) void k_binCount(const int* __restrict__ dst,
                                                  int* __restrict__ chist, int E, int nbk) {
    __shared__ int lcnt[BK_NODES];
    int t = threadIdx.x;
    for (int i = t; i < nbk; i += 512) lcnt[i] = 0;
    __syncthreads();
    int e0 = blockIdx.x * 2048;
    #pragma unroll
    for (int j = 0; j < 4; ++j) {
        int e = e0 + j * 512 + t;
        if (e < E) atomicAdd(&lcnt[dst[e] >> BK_SHIFT], 1);
    }
    __syncthreads();
    for (int i = t; i < nbk; i += 512)
        if (lcnt[i]) atomicAdd(&chist[i], lcnt[i]);
}

// ---------------- scan buckets -> bucketBase, cursor; rowstart[N]=E ----------------
__global__ __launch_bounds__(512) void k_scanChist(const int* __restrict__ chist,
                                                   int* __restrict__ base,
                                                   int* __restrict__ cursor,
                                                   int* __restrict__ rowstart,
                                                   int nbk, int N, int E) {
    __shared__ int s[512];
    int t = threadIdx.x;
    int v = (t < nbk) ? chist[t] : 0;
    s[t] = v;
    __syncthreads();
    for (int off = 1; off < 512; off <<= 1) {
        int u = (t >= off) ? s[t - off] : 0;
        __syncthreads();
        s[t] += u;
        __syncthreads();
    }
    int ex = s[t] - v;
    if (t < nbk) { base[t] = ex; cursor[t] = ex; }
    if (t == 0) { base[nbk] = E; rowstart[N] = E; }
}

// ---------------- pass 1: block-local counting sort into bucket regions ----------------
__global__ __launch_bounds__(512) void k_bin(const int* __restrict__ src,
                                             const int* __restrict__ dst,
                                             int* __restrict__ bucketCursor,
                                             int* __restrict__ pairBuf, int E, int nbk) {
    __shared__ int lcnt[BK_NODES];
    __shared__ int scanS[512];
    __shared__ int lofs[BK_NODES];
    __shared__ int delta[BK_NODES];
    __shared__ int sPack[2048];
    __shared__ unsigned short sBkt[2048];
    int t = threadIdx.x;
    int e0 = blockIdx.x * 2048;
    for (int i = t; i < nbk; i += 512) lcnt[i] = 0;
    __syncthreads();

    int mySrc[4], myB[4], myDl[4];
    #pragma unroll
    for (int j = 0; j < 4; ++j) {
        int e = e0 + j * 512 + t;
        if (e < E) {
            int sv = src[e], dv = dst[e];
            mySrc[j] = sv; myB[j] = dv >> BK_SHIFT; myDl[j] = dv & (BK_NODES - 1);
            atomicAdd(&lcnt[myB[j]], 1);
        } else myB[j] = -1;
    }
    __syncthreads();
    int v = (t < nbk) ? lcnt[t] : 0;
    scanS[t] = v;
    __syncthreads();
    for (int off = 1; off < 512; off <<= 1) {
        int u = (t >= off) ? scanS[t - off] : 0;
        __syncthreads();
        scanS[t] += u;
        __syncthreads();
    }
    if (t < nbk) lofs[t] = scanS[t] - v;
    __syncthreads();
    if (t < nbk) {
        int c = lcnt[t];
        int gb = (c > 0) ? atomicAdd(&bucketCursor[t], c) : 0;
        delta[t] = gb - lofs[t];
    }
    __syncthreads();
    #pragma unroll
    for (int j = 0; j < 4; ++j) {
        if (myB[j] >= 0) {
            int p = atomicAdd(&lofs[myB[j]], 1);
            sPack[p] = mySrc[j] | (myDl[j] << 18);   // src < 2^18
            sBkt[p] = (unsigned short)myB[j];
        }
    }
    __syncthreads();
    int total = (E - e0 < 2048) ? (E - e0) : 2048;
    for (int i = t; i < total; i += 512)
        pairBuf[delta[sBkt[i]] + i] = sPack[i];
}

// ---------------- pass 2: per-bucket node hist/scan -> rowstart,dinv; scatter csr ----------------
__global__ __launch_bounds__(256) void k_bscatter(const int* __restrict__ pairBuf,
                                                  const int* __restrict__ base,
                                                  int* __restrict__ rowstart,
                                                  float* __restrict__ dinv,
                                                  int* __restrict__ csr, int N) {
    int b = blockIdx.x;
    int n0 = b << BK_SHIFT;
    int n1 = n0 + BK_NODES; if (n1 > N) n1 = N;
    int nn = n1 - n0;
    __shared__ int hist[BK_NODES];
    __shared__ int curs[BK_NODES];
    __shared__ int ps[256];
    int t = threadIdx.x;
    for (int i = t; i < nn; i += 256) hist[i] = 0;
    __syncthreads();
    int e0 = base[b], e1 = base[b + 1];
    for (int e = e0 + t; e < e1; e += 256)
        atomicAdd(&hist[pairBuf[e] >> 18], 1);
    __syncthreads();
    int h0 = (2 * t < nn) ? hist[2 * t] : 0;
    int h1 = (2 * t + 1 < nn) ? hist[2 * t + 1] : 0;
    int p = h0 + h1;
    ps[t] = p;
    __syncthreads();
    for (int off = 1; off < 256; off <<= 1) {
        int u = (t >= off) ? ps[t - off] : 0;
        __syncthreads();
        ps[t] += u;
        __syncthreads();
    }
    int ex = ps[t] - p;
    if (2 * t < nn) {
        int r0 = e0 + ex;
        rowstart[n0 + 2 * t] = r0; curs[2 * t] = r0;
        dinv[n0 + 2 * t] = rsqrtf((float)(h0 + 1));
    }
    if (2 * t + 1 < nn) {
        int r1 = e0 + ex + h0;
        rowstart[n0 + 2 * t + 1] = r1; curs[2 * t + 1] = r1;
        dinv[n0 + 2 * t + 1] = rsqrtf((float)(h1 + 1));
    }
    __syncthreads();
    for (int e = e0 + t; e < e1; e += 256) {
        int pk = pairBuf[e];
        int pos = atomicAdd(&curs[pk >> 18], 1);
        csr[pos] = pk & 0x3FFFF;
    }
}

// ---------------- fused layer 1: gather (bf16) into LDS, then GEMM -> h1 ----------------
// Block: 256 thr, 64 nodes. Phase A: 4 waves gather 16 nodes each into sX.
// Phase B: 64x128 GEMM vs W1 (staged in sW), bias+relu, write h1.
__global__ __launch_bounds__(256) void k_layer1(const int* __restrict__ rowstart,
                                                const int* __restrict__ csr,
                                                const float* __restrict__ dinv,
                                                const unsigned int* __restrict__ xb,
                                                const float* __restrict__ x,
                                                const float* __restrict__ W1,
                                                const float* __restrict__ b1,
                                                float* __restrict__ h1, int N) {
    __shared__ float sX[64 * 68];     // aggX tile, padded ld=68
    __shared__ float sW[64 * 128];    // W1
    const int t = threadIdx.x;
    const int node0 = blockIdx.x * 64;

    // stage W1 while gathering addresses warm up
    for (int i = t; i < 2048; i += 256) {
        int k = i >> 5, c4 = i & 31;
        *(float4*)&sW[k * 128 + c4 * 4] = *(const float4*)&W1[k * 128 + c4 * 4];
    }

    // ---- phase A: gather ----
    const int w = t >> 6;
    const int l = t & 63;
    const int h = l >> 5;
    const int j = l & 31;
    for (int it = 0; it < 16; ++it) {
        const int r = w * 16 + it;
        const int node = node0 + r;
        if (node < N) {
            const int rs = rowstart[node];
            const int re = rowstart[node + 1];
            float accL = 0.0f, accH = 0.0f;
            for (int base = rs; base < re; base += 64) {
                int idx = base + l;
                int sE = (idx < re) ? csr[idx] : 0;
                float dE = (idx < re) ? dinv[sE] : 0.0f;
                int cnt = re - base; if (cnt > 64) cnt = 64;
                int iters = (cnt + 1) >> 1;
                for (int k = 0; k < iters; ++k) {
                    int e = 2 * k + h;
                    int sk = __shfl(sE, e);
                    float dk = __shfl(dE, e);
                    unsigned int u = xb[(size_t)sk * 32 + j];
                    accL += dk * __uint_as_float(u << 16);
                    accH += dk * __uint_as_float(u & 0xffff0000u);
                }
            }
            accL += __shfl_xor(accL, 32);
            accH += __shfl_xor(accH, 32);
            if (h == 0) {
                float dd = dinv[node];
                float2 xs = ((const float2*)x)[(size_t)node * 32 + j];
                sX[r * 68 + 2 * j]     = dd * accL + dd * dd * xs.x;
                sX[r * 68 + 2 * j + 1] = dd * accH + dd * dd * xs.y;
            }
        } else if (h == 0) {
            sX[r * 68 + 2 * j] = 0.0f;
            sX[r * 68 + 2 * j + 1] = 0.0f;
        }
    }
    __syncthreads();

    // ---- phase B: GEMM 64x128, K=64 ----
    const int rg = t >> 4;
    const int cg = t & 15;
    float acc[4][8];
    {
        float4 b01 = *(const float4*)&b1[cg * 8];
        float4 b23 = *(const float4*)&b1[cg * 8 + 4];
        #pragma unroll
        for (int jj = 0; jj < 4; ++jj) {
            acc[jj][0] = b01.x; acc[jj][1] = b01.y; acc[jj][2] = b01.z; acc[jj][3] = b01.w;
            acc[jj][4] = b23.x; acc[jj][5] = b23.y; acc[jj][6] = b23.z; acc[jj][7] = b23.w;
        }
    }
    for (int k0 = 0; k0 < 64; k0 += 4) {
        float4 a[4];
        #pragma unroll
        for (int jj = 0; jj < 4; ++jj) a[jj] = *(const float4*)&sX[(rg * 4 + jj) * 68 + k0];
        #pragma unroll
        for (int kk = 0; kk < 4; ++kk) {
            float4 w0 = *(const float4*)&sW[(k0 + kk) * 128 + cg * 8];
            float4 w1 = *(const float4*)&sW[(k0 + kk) * 128 + cg * 8 + 4];
            #pragma unroll
            for (int jj = 0; jj < 4; ++jj) {
                float f = ((const float*)&a[jj])[kk];
                acc[jj][0] += f * w0.x; acc[jj][1] += f * w0.y;
                acc[jj][2] += f * w0.z; acc[jj][3] += f * w0.w;
                acc[jj][4] += f * w1.x; acc[jj][5] += f * w1.y;
                acc[jj][6] += f * w1.z; acc[jj][7] += f * w1.w;
            }
        }
    }
    #pragma unroll
    for (int jj = 0; jj < 4; ++jj) {
        int row = node0 + rg * 4 + jj;
        if (row < N) {
            float4 o0, o1;
            o0.x = fmaxf(acc[jj][0], 0.f); o0.y = fmaxf(acc[jj][1], 0.f);
            o0.z = fmaxf(acc[jj][2], 0.f); o0.w = fmaxf(acc[jj][3], 0.f);
            o1.x = fmaxf(acc[jj][4], 0.f); o1.y = fmaxf(acc[jj][5], 0.f);
            o1.z = fmaxf(acc[jj][6], 0.f); o1.w = fmaxf(acc[jj][7], 0.f);
            *(float4*)&h1[(size_t)row * 128 + cg * 8] = o0;
            *(float4*)&h1[(size_t)row * 128 + cg * 8 + 4] = o1;
        }
    }
}

// ---------------- GEMM2: xs2b = bf16(dinv * (h1 @ W2)), packed 2/uint ----------------
__global__ __launch_bounds__(256) void k_gemm2bf(const float* __restrict__ X,
                                                 const float* __restrict__ W,
                                                 const float* __restrict__ rscale,
                                                 unsigned int* __restrict__ Yb, int N) {
    constexpr int K = 128, LDX = K + 4;
    __shared__ float sX[64 * LDX];
    __shared__ float sW[K * 64];
    const int t = threadIdx.x;
    const int row0 = blockIdx.x * 64;

    for (int i = t; i < K * 16; i += 256) {
        int k = i >> 4, cq = i & 15;
        *(float4*)&sW[k * 64 + cq * 4] = *(const float4*)&W[(size_t)k * 64 + cq * 4];
    }
    for (int i = t; i < 64 * (K / 4); i += 256) {
        int r = i / (K / 4), kq = i - r * (K / 4);
        int row = row0 + r;
        float4 xv = (row < N) ? *(const float4*)&X[(size_t)row * K + kq * 4]
                              : make_float4(0.f, 0.f, 0.f, 0.f);
        *(float4*)&sX[r * LDX + kq * 4] = xv;
    }
    __syncthreads();

    const int rg = t >> 4;
    const int cg = t & 15;
    float acc[4][4];
    #pragma unroll
    for (int jj = 0; jj < 4; ++jj)
        #pragma unroll
        for (int c = 0; c < 4; ++c) acc[jj][c] = 0.0f;

    for (int k0 = 0; k0 < K; k0 += 4) {
        float4 a[4], w[4];
        #pragma unroll
        for (int jj = 0; jj < 4; ++jj) a[jj] = *(const float4*)&sX[(rg * 4 + jj) * LDX + k0];
        #pragma unroll
        for (int kk = 0; kk < 4; ++kk) w[kk] = *(const float4*)&sW[(k0 + kk) * 64 + cg * 4];
        #pragma unroll
        for (int jj = 0; jj < 4; ++jj) {
            const float* aj = (const float*)&a[jj];
            #pragma unroll
            for (int kk = 0; kk < 4; ++kk) {
                float xr = aj[kk];
                acc[jj][0] += xr * w[kk].x;
                acc[jj][1] += xr * w[kk].y;
                acc[jj][2] += xr * w[kk].z;
                acc[jj][3] += xr * w[kk].w;
            }
        }
    }

    #pragma unroll
    for (int jj = 0; jj < 4; ++jj) {
        int row = row0 + rg * 4 + jj;
        if (row < N) {
            float sc = rscale[row];
            uint2 o;
            o.x = pack_bf16(acc[jj][0] * sc, acc[jj][1] * sc);
            o.y = pack_bf16(acc[jj][2] * sc, acc[jj][3] * sc);
            ((uint2*)Yb)[(size_t)row * 16 + cg] = o;
        }
    }
}

// ---------------- pruned gather2 + concat (bf16 rows): cB[b] = [h2(u), h2(i)] ----------------
// 256 thr = 2 pairs x 2 halves (waves). xs2b pre-scaled by dinv[src].
__global__ __launch_bounds__(256) void k_gather_pairs(const int* __restrict__ rowstart,
                                                      const int* __restrict__ csr,
                                                      const float* __restrict__ dinv,
                                                      const unsigned int* __restrict__ xs2b,
                                                      const float* __restrict__ b2,
                                                      const int* __restrict__ ui,
                                                      const int* __restrict__ ii,
                                                      float* __restrict__ cB, int B) {
    const int b = blockIdx.x * 2 + (threadIdx.x >> 7);
    const int half = (threadIdx.x >> 6) & 1;   // 0=user, 1=item
    const int l = threadIdx.x & 63;
    const int h = l >> 5;
    const int j = l & 31;
    if (b >= B) return;
    const int node = (half == 0) ? (ui[b] - 1) : (N_USERS_C + ii[b] - 1);
    const int rs = rowstart[node];
    const int re = rowstart[node + 1];

    float ax = 0.0f, ay = 0.0f;
    for (int base = rs; base < re; base += 64) {
        int idx = base + l;
        int sE = (idx < re) ? csr[idx] : 0;
        int cnt = re - base; if (cnt > 64) cnt = 64;
        int iters = (cnt + 1) >> 1;
        for (int k = 0; k < iters; ++k) {
            int e = 2 * k + h;
            if (e < cnt) {
                int sk = __shfl(sE, e);
                unsigned int u = xs2b[(size_t)sk * 32 + j];
                ax += __uint_as_float(u << 16);
                ay += __uint_as_float(u & 0xffff0000u);
            }
        }
    }
    ax += __shfl_xor(ax, 32);
    ay += __shfl_xor(ay, 32);
    if (h == 0) {
        float dd = dinv[node];
        unsigned int us = xs2b[(size_t)node * 32 + j];
        float2 bb = ((const float2*)b2)[j];
        float2 o;
        o.x = dd * (ax + __uint_as_float(us << 16)) + bb.x;
        o.y = dd * (ay + __uint_as_float(us & 0xffff0000u)) + bb.y;
        ((float2*)cB)[(size_t)b * 64 + half * 32 + j] = o;
    }
}

// ---------------- fused MLP: fc1+LN+ReLU+fc2+LN+ReLU+fc3+sigmoid ----------------
// Block: 256 thr, 64 rows. sIn/sW = 32KB each.
__global__ __launch_bounds__(256) void k_mlp(const float* __restrict__ cB,
                                             const float* __restrict__ fcW1, const float* __restrict__ fcb1,
                                             const float* __restrict__ g1,   const float* __restrict__ be1,
                                             const float* __restrict__ fcW2, const float* __restrict__ fcb2,
                                             const float* __restrict__ g2,   const float* __restrict__ be2,
                                             const float* __restrict__ fcW3, const float* __restrict__ fcb3,
                                             float* __restrict__ out) {
    __shared__ float sIn[64 * 128];
    __shared__ float sW[64 * 128];
    const int t = threadIdx.x;
    const int row0 = blockIdx.x * 64;
    const int rg = t >> 4;
    const int cg = t & 15;

    // load input tile
    for (int i = t; i < 2048; i += 256) {
        int r = i >> 5, c4 = i & 31;
        *(float4*)&sIn[r * 128 + c4 * 4] = *(const float4*)&cB[(size_t)(row0 + r) * 128 + c4 * 4];
    }

    // ---- fc1 (128->128) in two K-halves ----
    float acc1[4][8];
    {
        float4 b01 = *(const float4*)&fcb1[cg * 8];
        float4 b23 = *(const float4*)&fcb1[cg * 8 + 4];
        #pragma unroll
        for (int jj = 0; jj < 4; ++jj) {
            acc1[jj][0] = b01.x; acc1[jj][1] = b01.y; acc1[jj][2] = b01.z; acc1[jj][3] = b01.w;
            acc1[jj][4] = b23.x; acc1[jj][5] = b23.y; acc1[jj][6] = b23.z; acc1[jj][7] = b23.w;
        }
    }
    for (int s = 0; s < 2; ++s) {
        __syncthreads();
        for (int i = t; i < 2048; i += 256) {
            int k = i >> 5, c4 = i & 31;
            *(float4*)&sW[k * 128 + c4 * 4] = *(const float4*)&fcW1[(size_t)(64 * s + k) * 128 + c4 * 4];
        }
        __syncthreads();
        for (int k0 = 0; k0 < 64; k0 += 4) {
            float4 a[4];
            #pragma unroll
            for (int jj = 0; jj < 4; ++jj)
                a[jj] = *(const float4*)&sIn[(rg * 4 + jj) * 128 + 64 * s + k0];
            #pragma unroll
            for (int kk = 0; kk < 4; ++kk) {
                float4 w0 = *(const float4*)&sW[(k0 + kk) * 128 + cg * 8];
                float4 w1 = *(const float4*)&sW[(k0 + kk) * 128 + cg * 8 + 4];
                #pragma unroll
                for (int jj = 0; jj < 4; ++jj) {
                    float f = ((const float*)&a[jj])[kk];
                    acc1[jj][0] += f * w0.x; acc1[jj][1] += f * w0.y;
                    acc1[jj][2] += f * w0.z; acc1[jj][3] += f * w0.w;
                    acc1[jj][4] += f * w1.x; acc1[jj][5] += f * w1.y;
                    acc1[jj][6] += f * w1.z; acc1[jj][7] += f * w1.w;
                }
            }
        }
    }
    __syncthreads();

    // ---- LN(128)+ReLU, write z1 back into sIn ----
    {
        float4 g01 = *(const float4*)&g1[cg * 8];
        float4 g23 = *(const float4*)&g1[cg * 8 + 4];
        float4 e01 = *(const float4*)&be1[cg * 8];
        float4 e23 = *(const float4*)&be1[cg * 8 + 4];
        const float* gp = (const float*)&g01;  // g01,g23 contiguous? not guaranteed; index via arrays
        float gv[8] = {g01.x, g01.y, g01.z, g01.w, g23.x, g23.y, g23.z, g23.w};
        float ev[8] = {e01.x, e01.y, e01.z, e01.w, e23.x, e23.y, e23.z, e23.w};
        (void)gp;
        #pragma unroll
        for (int jj = 0; jj < 4; ++jj) {
            float s_ = 0.f, ss = 0.f;
            #pragma unroll
            for (int c = 0; c < 8; ++c) { float v = acc1[jj][c]; s_ += v; ss += v * v; }
            #pragma unroll
            for (int m = 1; m < 16; m <<= 1) { s_ += __shfl_xor(s_, m); ss += __shfl_xor(ss, m); }
            float mu = s_ * (1.0f / 128.0f);
            float var = ss * (1.0f / 128.0f) - mu * mu;
            float rs = rsqrtf(var + 1e-5f);
            #pragma unroll
            for (int c = 0; c < 8; ++c) {
                float z = (acc1[jj][c] - mu) * rs * gv[c] + ev[c];
                sIn[(rg * 4 + jj) * 128 + cg * 8 + c] = fmaxf(z, 0.f);
            }
        }
    }
    __syncthreads();

    // ---- fc2 (128->64): stage fcW2 fully ----
    for (int i = t; i < 2048; i += 256) {
        int k = i >> 4, c4 = i & 15;
        *(float4*)&sW[k * 64 + c4 * 4] = *(const float4*)&fcW2[(size_t)k * 64 + c4 * 4];
    }
    float acc2[4][4];
    {
        float4 bv = *(const float4*)&fcb2[cg * 4];
        #pragma unroll
        for (int jj = 0; jj < 4; ++jj) {
            acc2[jj][0] = bv.x; acc2[jj][1] = bv.y; acc2[jj][2] = bv.z; acc2[jj][3] = bv.w;
        }
    }
    __syncthreads();
    for (int k0 = 0; k0 < 128; k0 += 4) {
        float4 a[4], w[4];
        #pragma unroll
        for (int jj = 0; jj < 4; ++jj) a[jj] = *(const float4*)&sIn[(rg * 4 + jj) * 128 + k0];
        #pragma unroll
        for (int kk = 0; kk < 4; ++kk) w[kk] = *(const float4*)&sW[(k0 + kk) * 64 + cg * 4];
        #pragma unroll
        for (int jj = 0; jj < 4; ++jj) {
            const float* aj = (const float*)&a[jj];
            #pragma unroll
            for (int kk = 0; kk < 4; ++kk) {
                float f = aj[kk];
                acc2[jj][0] += f * w[kk].x; acc2[jj][1] += f * w[kk].y;
                acc2[jj][2] += f * w[kk].z; acc2[jj][3] += f * w[kk].w;
            }
        }
    }

    // ---- LN(64)+ReLU + head dot + sigmoid ----
    {
        float4 gv4 = *(const float4*)&g2[cg * 4];
        float4 ev4 = *(const float4*)&be2[cg * 4];
        float4 w34 = *(const float4*)&fcW3[cg * 4];
        float gv[4] = {gv4.x, gv4.y, gv4.z, gv4.w};
        float ev[4] = {ev4.x, ev4.y, ev4.z, ev4.w};
        float wv[4] = {w34.x, w34.y, w34.z, w34.w};
        float b3 = fcb3[0];
        #pragma unroll
        for (int jj = 0; jj < 4; ++jj) {
            float s_ = 0.f, ss = 0.f;
            #pragma unroll
            for (int c = 0; c < 4; ++c) { float v = acc2[jj][c]; s_ += v; ss += v * v; }
            #pragma unroll
            for (int m = 1; m < 16; m <<= 1) { s_ += __shfl_xor(s_, m); ss += __shfl_xor(ss, m); }
            float mu = s_ * (1.0f / 64.0f);
            float var = ss * (1.0f / 64.0f) - mu * mu;
            float rs = rsqrtf(var + 1e-5f);
            float p = 0.f;
            #pragma unroll
            for (int c = 0; c < 4; ++c) {
                float z = fmaxf((acc2[jj][c] - mu) * rs * gv[c] + ev[c], 0.f);
                p += z * wv[c];
            }
            #pragma unroll
            for (int m = 1; m < 16; m <<= 1) p += __shfl_xor(p, m);
            if (cg == 0) out[row0 + rg * 4 + jj] = 1.0f / (1.0f + expf(-(p + b3)));
        }
    }
}

extern "C" void kernel_launch(void* const* d_in, const int* in_sizes, int n_in,
                              void* d_out, int out_size, void* d_ws, size_t ws_size,
                              hipStream_t stream) {
    const float* x    = (const float*)d_in[0];
    const int*   src  = (const int*)d_in[1];
    const int*   dst  = (const int*)d_in[2];
    const int*   ui   = (const int*)d_in[3];
    const int*   ii   = (const int*)d_in[4];
    const float* W1   = (const float*)d_in[5];
    const float* b1   = (const float*)d_in[6];
    const float* W2   = (const float*)d_in[7];
    const float* b2   = (const float*)d_in[8];
    const float* fcW1 = (const float*)d_in[9];
    const float* fcb1 = (const float*)d_in[10];
    const float* g1   = (const float*)d_in[11];
    const float* be1  = (const float*)d_in[12];
    const float* fcW2 = (const float*)d_in[13];
    const float* fcb2 = (const float*)d_in[14];
    const float* g2   = (const float*)d_in[15];
    const float* be2  = (const float*)d_in[16];
    const float* fcW3 = (const float*)d_in[17];
    const float* fcb3 = (const float*)d_in[18];
    float* out = (float*)d_out;

    const int N = in_sizes[0] / 64;          // 150000
    const int E = in_sizes[1];               // 2400000
    const int B = in_sizes[3];               // 16384
    const int NBK = (N + BK_NODES - 1) >> BK_SHIFT;   // 293
    const int EB = (E + 2047) / 2048;

    // ---- workspace layout (~145 MB; 154 MB proven available in round 1) ----
    float* ws   = (float*)d_ws;
    float* dinv = ws;                                   // N
    int* rowstart = (int*)(dinv + N);                   // N+1
    int* csr      = rowstart + (N + 1);                 // E
    unsigned int* xb = (unsigned int*)(csr + E);        // N*32 (bf16 x, 19.2MB)
    float* bufA = (float*)(xb + (size_t)N * 32);        // N*64 f32: pairBuf scratch, then xs2b
    float* bufH = bufA + (size_t)N * 64;                // N*128 f32: h1, then cB
    int* pairBuf = (int*)bufA;                          // E
    int* chist   = pairBuf + E;                         // 512
    int* bbase   = chist + 512;                         // 513
    int* bcursor = bbase + 513;                         // 512
    unsigned int* xs2b = (unsigned int*)bufA;           // N*32 (bf16 xs2)
    float* cB = bufH;                                   // B*128 (h1 dead after gemm2)

    // ---- bf16 copy of x ----
    k_tobf16<<<(N * 32 + 255) / 256, 256, 0, stream>>>(x, xb, N * 32);

    // ---- CSR build ----
    k_zero_i<<<2, 256, 0, stream>>>(chist, 512);
    k_binCount<<<EB, 512, 0, stream>>>(dst, chist, E, NBK);
    k_scanChist<<<1, 512, 0, stream>>>(chist, bbase, bcursor, rowstart, NBK, N, E);
    k_bin<<<EB, 512, 0, stream>>>(src, dst, bcursor, pairBuf, E, NBK);
    k_bscatter<<<NBK, 256, 0, stream>>>(pairBuf, bbase, rowstart, dinv, csr, N);

    // ---- fused layer 1: h1 = relu((A_hat x) @ W1 + b1) ----
    k_layer1<<<(N + 63) / 64, 256, 0, stream>>>(rowstart, csr, dinv, xb, x, W1, b1, bufH, N);

    // ---- layer 2: xs2b = bf16(dinv * (h1 @ W2)); pruned gather + concat -> cB ----
    k_gemm2bf<<<(N + 63) / 64, 256, 0, stream>>>(bufH, W2, dinv, xs2b, N);
    k_gather_pairs<<<(B + 1) / 2, 256, 0, stream>>>(rowstart, csr, dinv, xs2b, b2, ui, ii, cB, B);

    // ---- fused MLP ----
    k_mlp<<<B / 64, 256, 0, stream>>>(cB, fcW1, fcb1, g1, be1,
                                      fcW2, fcb2, g2, be2, fcW3, fcb3, out);
}

// Round 7
// 482.532 us; speedup vs baseline: 1.3202x; 1.3202x over previous
//
#include <hip/hip_runtime.h>
#include <hip/hip_bf16.h>
#include <math.h>

#define N_USERS_C 100000
#define BK_SHIFT 9
#define BK_NODES 512

__device__ __forceinline__ unsigned int pack_bf16(float a, float b) {
    __hip_bfloat16 ha = __float2bfloat16(a), hb = __float2bfloat16(b);
    return ((unsigned int)(*(unsigned short*)&hb) << 16) | (unsigned int)(*(unsigned short*)&ha);
}
__device__ __forceinline__ float bf_lo(unsigned int u) { return __uint_as_float(u << 16); }
__device__ __forceinline__ float bf_hi(unsigned int u) { return __uint_as_float(u & 0xffff0000u); }

// ---------------- small helpers ----------------
__global__ void k_zero_i(int* __restrict__ p, int n) {
    int i = blockIdx.x * 256 + threadIdx.x;
    if (i < n) p[i] = 0;
}

// x (f32) -> packed bf16x2 (RNE)
__global__ void k_tobf16(const float* __restrict__ x, unsigned int* __restrict__ xb, int n2) {
    int i = blockIdx.x * 256 + threadIdx.x;
    if (i >= n2) return;
    float2 v = ((const float2*)x)[i];
    xb[i] = pack_bf16(v.x, v.y);
}

// ---------------- pass 0: coarse histogram over buckets ----------------
__global__ __launch_bounds__(512) void k_binCount(const int* __restrict__ dst,
                                                  int* __restrict__ chist, int E, int nbk) {
    __shared__ int lcnt[BK_NODES];
    int t = threadIdx.x;
    for (int i = t; i < nbk; i += 512) lcnt[i] = 0;
    __syncthreads();
    int e0 = blockIdx.x * 2048;
    #pragma unroll
    for (int j = 0; j < 4; ++j) {
        int e = e0 + j * 512 + t;
        if (e < E) atomicAdd(&lcnt[dst[e] >> BK_SHIFT], 1);
    }
    __syncthreads();
    for (int i = t; i < nbk; i += 512)
        if (lcnt[i]) atomicAdd(&chist[i], lcnt[i]);
}

// ---------------- scan buckets -> bucketBase, cursor; rowstart[N]=E ----------------
__global__ __launch_bounds__(512) void k_scanChist(const int* __restrict__ chist,
                                                   int* __restrict__ base,
                                                   int* __restrict__ cursor,
                                                   int* __restrict__ rowstart,
                                                   int nbk, int N, int E) {
    __shared__ int s[512];
    int t = threadIdx.x;
    int v = (t < nbk) ? chist[t] : 0;
    s[t] = v;
    __syncthreads();
    for (int off = 1; off < 512; off <<= 1) {
        int u = (t >= off) ? s[t - off] : 0;
        __syncthreads();
        s[t] += u;
        __syncthreads();
    }
    int ex = s[t] - v;
    if (t < nbk) { base[t] = ex; cursor[t] = ex; }
    if (t == 0) { base[nbk] = E; rowstart[N] = E; }
}

// ---------------- pass 1: block-local counting sort into bucket regions ----------------
__global__ __launch_bounds__(512) void k_bin(const int* __restrict__ src,
                                             const int* __restrict__ dst,
                                             int* __restrict__ bucketCursor,
                                             int* __restrict__ pairBuf, int E, int nbk) {
    __shared__ int lcnt[BK_NODES];
    __shared__ int scanS[512];
    __shared__ int lofs[BK_NODES];
    __shared__ int delta[BK_NODES];
    __shared__ int sPack[2048];
    __shared__ unsigned short sBkt[2048];
    int t = threadIdx.x;
    int e0 = blockIdx.x * 2048;
    for (int i = t; i < nbk; i += 512) lcnt[i] = 0;
    __syncthreads();

    int mySrc[4], myB[4], myDl[4];
    #pragma unroll
    for (int j = 0; j < 4; ++j) {
        int e = e0 + j * 512 + t;
        if (e < E) {
            int sv = src[e], dv = dst[e];
            mySrc[j] = sv; myB[j] = dv >> BK_SHIFT; myDl[j] = dv & (BK_NODES - 1);
            atomicAdd(&lcnt[myB[j]], 1);
        } else myB[j] = -1;
    }
    __syncthreads();
    int v = (t < nbk) ? lcnt[t] : 0;
    scanS[t] = v;
    __syncthreads();
    for (int off = 1; off < 512; off <<= 1) {
        int u = (t >= off) ? scanS[t - off] : 0;
        __syncthreads();
        scanS[t] += u;
        __syncthreads();
    }
    if (t < nbk) lofs[t] = scanS[t] - v;
    __syncthreads();
    if (t < nbk) {
        int c = lcnt[t];
        int gb = (c > 0) ? atomicAdd(&bucketCursor[t], c) : 0;
        delta[t] = gb - lofs[t];
    }
    __syncthreads();
    #pragma unroll
    for (int j = 0; j < 4; ++j) {
        if (myB[j] >= 0) {
            int p = atomicAdd(&lofs[myB[j]], 1);
            sPack[p] = mySrc[j] | (myDl[j] << 18);   // src < 2^18
            sBkt[p] = (unsigned short)myB[j];
        }
    }
    __syncthreads();
    int total = (E - e0 < 2048) ? (E - e0) : 2048;
    for (int i = t; i < total; i += 512)
        pairBuf[delta[sBkt[i]] + i] = sPack[i];
}

// ---------------- pass 2: per-bucket node hist/scan -> rowstart,dinv; scatter csr ----------------
__global__ __launch_bounds__(256) void k_bscatter(const int* __restrict__ pairBuf,
                                                  const int* __restrict__ base,
                                                  int* __restrict__ rowstart,
                                                  float* __restrict__ dinv,
                                                  int* __restrict__ csr, int N) {
    int b = blockIdx.x;
    int n0 = b << BK_SHIFT;
    int n1 = n0 + BK_NODES; if (n1 > N) n1 = N;
    int nn = n1 - n0;
    __shared__ int hist[BK_NODES];
    __shared__ int curs[BK_NODES];
    __shared__ int ps[256];
    int t = threadIdx.x;
    for (int i = t; i < nn; i += 256) hist[i] = 0;
    __syncthreads();
    int e0 = base[b], e1 = base[b + 1];
    for (int e = e0 + t; e < e1; e += 256)
        atomicAdd(&hist[pairBuf[e] >> 18], 1);
    __syncthreads();
    int h0 = (2 * t < nn) ? hist[2 * t] : 0;
    int h1 = (2 * t + 1 < nn) ? hist[2 * t + 1] : 0;
    int p = h0 + h1;
    ps[t] = p;
    __syncthreads();
    for (int off = 1; off < 256; off <<= 1) {
        int u = (t >= off) ? ps[t - off] : 0;
        __syncthreads();
        ps[t] += u;
        __syncthreads();
    }
    int ex = ps[t] - p;
    if (2 * t < nn) {
        int r0 = e0 + ex;
        rowstart[n0 + 2 * t] = r0; curs[2 * t] = r0;
        dinv[n0 + 2 * t] = rsqrtf((float)(h0 + 1));
    }
    if (2 * t + 1 < nn) {
        int r1 = e0 + ex + h0;
        rowstart[n0 + 2 * t + 1] = r1; curs[2 * t + 1] = r1;
        dinv[n0 + 2 * t + 1] = rsqrtf((float)(h1 + 1));
    }
    __syncthreads();
    for (int e = e0 + t; e < e1; e += 256) {
        int pk = pairBuf[e];
        int pos = atomicAdd(&curs[pk >> 18], 1);
        csr[pos] = pk & 0x3FFFF;
    }
}

// ---------------- gather1: aggX = A_hat x, bf16 rows, 2 edges/iter ----------------
// standalone, 0 LDS / 12 VGPR -> high occupancy for latency hiding.
__global__ __launch_bounds__(256) void k_gather1(const int* __restrict__ rowstart,
                                                 const int* __restrict__ csr,
                                                 const float* __restrict__ dinv,
                                                 const unsigned int* __restrict__ xb,
                                                 const float* __restrict__ x,
                                                 float* __restrict__ out, int N) {
    const int node = blockIdx.x * 4 + (threadIdx.x >> 6);
    const int l = threadIdx.x & 63;
    if (node >= N) return;
    const int h = l >> 5;
    const int j = l & 31;
    const int rs = rowstart[node];
    const int re = rowstart[node + 1];

    float accL = 0.0f, accH = 0.0f;
    for (int base = rs; base < re; base += 64) {
        int idx = base + l;
        int sE = (idx < re) ? csr[idx] : 0;
        float dE = (idx < re) ? dinv[sE] : 0.0f;   // 0 => no contribution
        int cnt = re - base; if (cnt > 64) cnt = 64;
        int iters = (cnt + 1) >> 1;
        for (int k = 0; k < iters; ++k) {
            int e = 2 * k + h;
            int sk = __shfl(sE, e);
            float dk = __shfl(dE, e);
            unsigned int u = xb[(size_t)sk * 32 + j];
            accL += dk * bf_lo(u);
            accH += dk * bf_hi(u);
        }
    }
    accL += __shfl_xor(accL, 32);
    accH += __shfl_xor(accH, 32);
    if (h == 0) {
        float dd = dinv[node];
        float2 xs = ((const float2*)x)[(size_t)node * 32 + j];   // exact f32 self term
        float2 o;
        o.x = dd * accL + dd * dd * xs.x;
        o.y = dd * accH + dd * dd * xs.y;
        ((float2*)out)[(size_t)node * 32 + j] = o;
    }
}

// ---------------- GEMM1: h1b = bf16(relu(aggX @ W1 + b1)), K=64 ----------------
// grid (N/64, 2); output row = 64 uints (128 bf16).
__global__ __launch_bounds__(256) void k_gemm1bf(const float* __restrict__ X,
                                                 const float* __restrict__ W1,
                                                 const float* __restrict__ b1,
                                                 unsigned int* __restrict__ Yb, int N) {
    constexpr int K = 64, LDX = K + 4;
    __shared__ float sX[64 * LDX];
    __shared__ float sW[K * 64];
    const int t = threadIdx.x;
    const int row0 = blockIdx.x * 64;
    const int c0 = blockIdx.y * 64;

    for (int i = t; i < K * 16; i += 256) {
        int k = i >> 4, cq = i & 15;
        *(float4*)&sW[k * 64 + cq * 4] = *(const float4*)&W1[(size_t)k * 128 + c0 + cq * 4];
    }
    for (int i = t; i < 64 * (K / 4); i += 256) {
        int r = i / (K / 4), kq = i - r * (K / 4);
        int row = row0 + r;
        float4 xv = (row < N) ? *(const float4*)&X[(size_t)row * K + kq * 4]
                              : make_float4(0.f, 0.f, 0.f, 0.f);
        *(float4*)&sX[r * LDX + kq * 4] = xv;
    }
    __syncthreads();

    const int rg = t >> 4;
    const int cg = t & 15;
    float acc[4][4];
    {
        float4 bv = *(const float4*)&b1[c0 + cg * 4];
        #pragma unroll
        for (int jj = 0; jj < 4; ++jj) {
            acc[jj][0] = bv.x; acc[jj][1] = bv.y; acc[jj][2] = bv.z; acc[jj][3] = bv.w;
        }
    }
    for (int k0 = 0; k0 < K; k0 += 4) {
        float4 a[4], w[4];
        #pragma unroll
        for (int jj = 0; jj < 4; ++jj) a[jj] = *(const float4*)&sX[(rg * 4 + jj) * LDX + k0];
        #pragma unroll
        for (int kk = 0; kk < 4; ++kk) w[kk] = *(const float4*)&sW[(k0 + kk) * 64 + cg * 4];
        #pragma unroll
        for (int jj = 0; jj < 4; ++jj) {
            const float* aj = (const float*)&a[jj];
            #pragma unroll
            for (int kk = 0; kk < 4; ++kk) {
                float f = aj[kk];
                acc[jj][0] += f * w[kk].x; acc[jj][1] += f * w[kk].y;
                acc[jj][2] += f * w[kk].z; acc[jj][3] += f * w[kk].w;
            }
        }
    }
    #pragma unroll
    for (int jj = 0; jj < 4; ++jj) {
        int row = row0 + rg * 4 + jj;
        if (row < N) {
            uint2 o;
            o.x = pack_bf16(fmaxf(acc[jj][0], 0.f), fmaxf(acc[jj][1], 0.f));
            o.y = pack_bf16(fmaxf(acc[jj][2], 0.f), fmaxf(acc[jj][3], 0.f));
            *(uint2*)&Yb[(size_t)row * 64 + (c0 >> 1) + cg * 2] = o;
        }
    }
}

// ---------------- GEMM2: xs2b = bf16(dinv * (h1b @ W2)), K=128 bf16 input ----------------
__global__ __launch_bounds__(256) void k_gemm2bf(const unsigned int* __restrict__ Xb,
                                                 const float* __restrict__ W,
                                                 const float* __restrict__ rscale,
                                                 unsigned int* __restrict__ Yb, int N) {
    constexpr int K = 128, LDX = K + 4;
    __shared__ float sX[64 * LDX];
    __shared__ float sW[K * 64];
    const int t = threadIdx.x;
    const int row0 = blockIdx.x * 64;

    for (int i = t; i < K * 16; i += 256) {
        int k = i >> 4, cq = i & 15;
        *(float4*)&sW[k * 64 + cq * 4] = *(const float4*)&W[(size_t)k * 64 + cq * 4];
    }
    // stage h1b: 64 rows x 16 uint2 (4 bf16 each)
    for (int i = t; i < 64 * 16; i += 256) {
        int r = i >> 4, q = i & 15;
        int row = row0 + r;
        uint2 u = (row < N) ? *(const uint2*)&Xb[(size_t)row * 64 + q * 4]
                            : make_uint2(0u, 0u);
        float4 xv;
        xv.x = bf_lo(u.x); xv.y = bf_hi(u.x);
        xv.z = bf_lo(u.y); xv.w = bf_hi(u.y);
        *(float4*)&sX[r * LDX + q * 8] = xv;
        uint2 u2 = (row < N) ? *(const uint2*)&Xb[(size_t)row * 64 + q * 4 + 2]
                             : make_uint2(0u, 0u);
        float4 xv2;
        xv2.x = bf_lo(u2.x); xv2.y = bf_hi(u2.x);
        xv2.z = bf_lo(u2.y); xv2.w = bf_hi(u2.y);
        *(float4*)&sX[r * LDX + q * 8 + 4] = xv2;
    }
    __syncthreads();

    const int rg = t >> 4;
    const int cg = t & 15;
    float acc[4][4];
    #pragma unroll
    for (int jj = 0; jj < 4; ++jj)
        #pragma unroll
        for (int c = 0; c < 4; ++c) acc[jj][c] = 0.0f;

    for (int k0 = 0; k0 < K; k0 += 4) {
        float4 a[4], w[4];
        #pragma unroll
        for (int jj = 0; jj < 4; ++jj) a[jj] = *(const float4*)&sX[(rg * 4 + jj) * LDX + k0];
        #pragma unroll
        for (int kk = 0; kk < 4; ++kk) w[kk] = *(const float4*)&sW[(k0 + kk) * 64 + cg * 4];
        #pragma unroll
        for (int jj = 0; jj < 4; ++jj) {
            const float* aj = (const float*)&a[jj];
            #pragma unroll
            for (int kk = 0; kk < 4; ++kk) {
                float f = aj[kk];
                acc[jj][0] += f * w[kk].x; acc[jj][1] += f * w[kk].y;
                acc[jj][2] += f * w[kk].z; acc[jj][3] += f * w[kk].w;
            }
        }
    }
    #pragma unroll
    for (int jj = 0; jj < 4; ++jj) {
        int row = row0 + rg * 4 + jj;
        if (row < N) {
            float sc = rscale[row];
            uint2 o;
            o.x = pack_bf16(acc[jj][0] * sc, acc[jj][1] * sc);
            o.y = pack_bf16(acc[jj][2] * sc, acc[jj][3] * sc);
            ((uint2*)Yb)[(size_t)row * 16 + cg] = o;
        }
    }
}

// ---------------- pruned gather2 + concat (bf16 rows): cB[b] = [h2(u), h2(i)] ----------------
__global__ __launch_bounds__(256) void k_gather_pairs(const int* __restrict__ rowstart,
                                                      const int* __restrict__ csr,
                                                      const float* __restrict__ dinv,
                                                      const unsigned int* __restrict__ xs2b,
                                                      const float* __restrict__ b2,
                                                      const int* __restrict__ ui,
                                                      const int* __restrict__ ii,
                                                      float* __restrict__ cB, int B) {
    const int b = blockIdx.x * 2 + (threadIdx.x >> 7);
    const int half = (threadIdx.x >> 6) & 1;   // 0=user, 1=item
    const int l = threadIdx.x & 63;
    const int h = l >> 5;
    const int j = l & 31;
    if (b >= B) return;
    const int node = (half == 0) ? (ui[b] - 1) : (N_USERS_C + ii[b] - 1);
    const int rs = rowstart[node];
    const int re = rowstart[node + 1];

    float ax = 0.0f, ay = 0.0f;
    for (int base = rs; base < re; base += 64) {
        int idx = base + l;
        int sE = (idx < re) ? csr[idx] : 0;
        int cnt = re - base; if (cnt > 64) cnt = 64;
        int iters = (cnt + 1) >> 1;
        for (int k = 0; k < iters; ++k) {
            int e = 2 * k + h;
            if (e < cnt) {
                int sk = __shfl(sE, e);
                unsigned int u = xs2b[(size_t)sk * 32 + j];
                ax += bf_lo(u);
                ay += bf_hi(u);
            }
        }
    }
    ax += __shfl_xor(ax, 32);
    ay += __shfl_xor(ay, 32);
    if (h == 0) {
        float dd = dinv[node];
        unsigned int us = xs2b[(size_t)node * 32 + j];
        float2 bb = ((const float2*)b2)[j];
        float2 o;
        o.x = dd * (ax + bf_lo(us)) + bb.x;
        o.y = dd * (ay + bf_hi(us)) + bb.y;
        ((float2*)cB)[(size_t)b * 64 + half * 32 + j] = o;
    }
}

// ---------------- fused MLP: fc1+LN+ReLU+fc2+LN+ReLU+fc3+sigmoid ----------------
__global__ __launch_bounds__(256) void k_mlp(const float* __restrict__ cB,
                                             const float* __restrict__ fcW1, const float* __restrict__ fcb1,
                                             const float* __restrict__ g1,   const float* __restrict__ be1,
                                             const float* __restrict__ fcW2, const float* __restrict__ fcb2,
                                             const float* __restrict__ g2,   const float* __restrict__ be2,
                                             const float* __restrict__ fcW3, const float* __restrict__ fcb3,
                                             float* __restrict__ out) {
    __shared__ float sIn[64 * 128];
    __shared__ float sW[64 * 128];
    const int t = threadIdx.x;
    const int row0 = blockIdx.x * 64;
    const int rg = t >> 4;
    const int cg = t & 15;

    for (int i = t; i < 2048; i += 256) {
        int r = i >> 5, c4 = i & 31;
        *(float4*)&sIn[r * 128 + c4 * 4] = *(const float4*)&cB[(size_t)(row0 + r) * 128 + c4 * 4];
    }

    // ---- fc1 (128->128) in two K-halves ----
    float acc1[4][8];
    {
        float4 b01 = *(const float4*)&fcb1[cg * 8];
        float4 b23 = *(const float4*)&fcb1[cg * 8 + 4];
        #pragma unroll
        for (int jj = 0; jj < 4; ++jj) {
            acc1[jj][0] = b01.x; acc1[jj][1] = b01.y; acc1[jj][2] = b01.z; acc1[jj][3] = b01.w;
            acc1[jj][4] = b23.x; acc1[jj][5] = b23.y; acc1[jj][6] = b23.z; acc1[jj][7] = b23.w;
        }
    }
    for (int s = 0; s < 2; ++s) {
        __syncthreads();
        for (int i = t; i < 2048; i += 256) {
            int k = i >> 5, c4 = i & 31;
            *(float4*)&sW[k * 128 + c4 * 4] = *(const float4*)&fcW1[(size_t)(64 * s + k) * 128 + c4 * 4];
        }
        __syncthreads();
        for (int k0 = 0; k0 < 64; k0 += 4) {
            float4 a[4];
            #pragma unroll
            for (int jj = 0; jj < 4; ++jj)
                a[jj] = *(const float4*)&sIn[(rg * 4 + jj) * 128 + 64 * s + k0];
            #pragma unroll
            for (int kk = 0; kk < 4; ++kk) {
                float4 w0 = *(const float4*)&sW[(k0 + kk) * 128 + cg * 8];
                float4 w1 = *(const float4*)&sW[(k0 + kk) * 128 + cg * 8 + 4];
                #pragma unroll
                for (int jj = 0; jj < 4; ++jj) {
                    float f = ((const float*)&a[jj])[kk];
                    acc1[jj][0] += f * w0.x; acc1[jj][1] += f * w0.y;
                    acc1[jj][2] += f * w0.z; acc1[jj][3] += f * w0.w;
                    acc1[jj][4] += f * w1.x; acc1[jj][5] += f * w1.y;
                    acc1[jj][6] += f * w1.z; acc1[jj][7] += f * w1.w;
                }
            }
        }
    }
    __syncthreads();

    // ---- LN(128)+ReLU -> sIn ----
    {
        float4 g01 = *(const float4*)&g1[cg * 8];
        float4 g23 = *(const float4*)&g1[cg * 8 + 4];
        float4 e01 = *(const float4*)&be1[cg * 8];
        float4 e23 = *(const float4*)&be1[cg * 8 + 4];
        float gv[8] = {g01.x, g01.y, g01.z, g01.w, g23.x, g23.y, g23.z, g23.w};
        float ev[8] = {e01.x, e01.y, e01.z, e01.w, e23.x, e23.y, e23.z, e23.w};
        #pragma unroll
        for (int jj = 0; jj < 4; ++jj) {
            float s_ = 0.f, ss = 0.f;
            #pragma unroll
            for (int c = 0; c < 8; ++c) { float v = acc1[jj][c]; s_ += v; ss += v * v; }
            #pragma unroll
            for (int m = 1; m < 16; m <<= 1) { s_ += __shfl_xor(s_, m); ss += __shfl_xor(ss, m); }
            float mu = s_ * (1.0f / 128.0f);
            float var = ss * (1.0f / 128.0f) - mu * mu;
            float rs = rsqrtf(var + 1e-5f);
            #pragma unroll
            for (int c = 0; c < 8; ++c) {
                float z = (acc1[jj][c] - mu) * rs * gv[c] + ev[c];
                sIn[(rg * 4 + jj) * 128 + cg * 8 + c] = fmaxf(z, 0.f);
            }
        }
    }
    __syncthreads();

    // ---- fc2 (128->64) ----
    for (int i = t; i < 2048; i += 256) {
        int k = i >> 4, c4 = i & 15;
        *(float4*)&sW[k * 64 + c4 * 4] = *(const float4*)&fcW2[(size_t)k * 64 + c4 * 4];
    }
    float acc2[4][4];
    {
        float4 bv = *(const float4*)&fcb2[cg * 4];
        #pragma unroll
        for (int jj = 0; jj < 4; ++jj) {
            acc2[jj][0] = bv.x; acc2[jj][1] = bv.y; acc2[jj][2] = bv.z; acc2[jj][3] = bv.w;
        }
    }
    __syncthreads();
    for (int k0 = 0; k0 < 128; k0 += 4) {
        float4 a[4], w[4];
        #pragma unroll
        for (int jj = 0; jj < 4; ++jj) a[jj] = *(const float4*)&sIn[(rg * 4 + jj) * 128 + k0];
        #pragma unroll
        for (int kk = 0; kk < 4; ++kk) w[kk] = *(const float4*)&sW[(k0 + kk) * 64 + cg * 4];
        #pragma unroll
        for (int jj = 0; jj < 4; ++jj) {
            const float* aj = (const float*)&a[jj];
            #pragma unroll
            for (int kk = 0; kk < 4; ++kk) {
                float f = aj[kk];
                acc2[jj][0] += f * w[kk].x; acc2[jj][1] += f * w[kk].y;
                acc2[jj][2] += f * w[kk].z; acc2[jj][3] += f * w[kk].w;
            }
        }
    }

    // ---- LN(64)+ReLU + head dot + sigmoid ----
    {
        float4 gv4 = *(const float4*)&g2[cg * 4];
        float4 ev4 = *(const float4*)&be2[cg * 4];
        float4 w34 = *(const float4*)&fcW3[cg * 4];
        float gv[4] = {gv4.x, gv4.y, gv4.z, gv4.w};
        float ev[4] = {ev4.x, ev4.y, ev4.z, ev4.w};
        float wv[4] = {w34.x, w34.y, w34.z, w34.w};
        float b3 = fcb3[0];
        #pragma unroll
        for (int jj = 0; jj < 4; ++jj) {
            float s_ = 0.f, ss = 0.f;
            #pragma unroll
            for (int c = 0; c < 4; ++c) { float v = acc2[jj][c]; s_ += v; ss += v * v; }
            #pragma unroll
            for (int m = 1; m < 16; m <<= 1) { s_ += __shfl_xor(s_, m); ss += __shfl_xor(ss, m); }
            float mu = s_ * (1.0f / 64.0f);
            float var = ss * (1.0f / 64.0f) - mu * mu;
            float rs = rsqrtf(var + 1e-5f);
            float p = 0.f;
            #pragma unroll
            for (int c = 0; c < 4; ++c) {
                float z = fmaxf((acc2[jj][c] - mu) * rs * gv[c] + ev[c], 0.f);
                p += z * wv[c];
            }
            #pragma unroll
            for (int m = 1; m < 16; m <<= 1) p += __shfl_xor(p, m);
            if (cg == 0) out[row0 + rg * 4 + jj] = 1.0f / (1.0f + expf(-(p + b3)));
        }
    }
}

extern "C" void kernel_launch(void* const* d_in, const int* in_sizes, int n_in,
                              void* d_out, int out_size, void* d_ws, size_t ws_size,
                              hipStream_t stream) {
    const float* x    = (const float*)d_in[0];
    const int*   src  = (const int*)d_in[1];
    const int*   dst  = (const int*)d_in[2];
    const int*   ui   = (const int*)d_in[3];
    const int*   ii   = (const int*)d_in[4];
    const float* W1   = (const float*)d_in[5];
    const float* b1   = (const float*)d_in[6];
    const float* W2   = (const float*)d_in[7];
    const float* b2   = (const float*)d_in[8];
    const float* fcW1 = (const float*)d_in[9];
    const float* fcb1 = (const float*)d_in[10];
    const float* g1   = (const float*)d_in[11];
    const float* be1  = (const float*)d_in[12];
    const float* fcW2 = (const float*)d_in[13];
    const float* fcb2 = (const float*)d_in[14];
    const float* g2   = (const float*)d_in[15];
    const float* be2  = (const float*)d_in[16];
    const float* fcW3 = (const float*)d_in[17];
    const float* fcb3 = (const float*)d_in[18];
    float* out = (float*)d_out;

    const int N = in_sizes[0] / 64;          // 150000
    const int E = in_sizes[1];               // 2400000
    const int B = in_sizes[3];               // 16384
    const int NBK = (N + BK_NODES - 1) >> BK_SHIFT;   // 293
    const int EB = (E + 2047) / 2048;

    // ---- workspace layout (~88 MB) ----
    float* ws   = (float*)d_ws;
    float* dinv = ws;                                   // N
    int* rowstart = (int*)(dinv + N);                   // N+1
    int* csr      = rowstart + (N + 1);                 // E
    unsigned int* xb = (unsigned int*)(csr + E);        // N*32 (bf16 x)
    float* bufA = (float*)(xb + (size_t)N * 32);        // N*64 f32: CSR scratch -> aggX -> xs2b+cB
    unsigned int* h1b = (unsigned int*)(bufA + (size_t)N * 64);  // N*64 uints (bf16 h1)
    // CSR-build scratch aliased inside bufA (dead before aggX is written)
    int* pairBuf = (int*)bufA;                          // E
    int* chist   = pairBuf + E;                         // 512
    int* bbase   = chist + 512;                         // 513
    int* bcursor = bbase + 513;                         // 512
    // after GEMM1, aggX (bufA) is dead: xs2b + cB alias it
    unsigned int* xs2b = (unsigned int*)bufA;           // N*32 uints
    float* cB = (float*)(xs2b + (size_t)N * 32);        // B*128 f32 (fits: N*32 floats left)

    // ---- bf16 copy of x ----
    k_tobf16<<<(N * 32 + 255) / 256, 256, 0, stream>>>(x, xb, N * 32);

    // ---- CSR build ----
    k_zero_i<<<2, 256, 0, stream>>>(chist, 512);
    k_binCount<<<EB, 512, 0, stream>>>(dst, chist, E, NBK);
    k_scanChist<<<1, 512, 0, stream>>>(chist, bbase, bcursor, rowstart, NBK, N, E);
    k_bin<<<EB, 512, 0, stream>>>(src, dst, bcursor, pairBuf, E, NBK);
    k_bscatter<<<NBK, 256, 0, stream>>>(pairBuf, bbase, rowstart, dinv, csr, N);

    // ---- layer 1: aggX = A_hat x ; h1b = bf16(relu(aggX @ W1 + b1)) ----
    k_gather1<<<(N + 3) / 4, 256, 0, stream>>>(rowstart, csr, dinv, xb, x, bufA, N);
    k_gemm1bf<<<dim3((N + 63) / 64, 2), 256, 0, stream>>>(bufA, W1, b1, h1b, N);

    // ---- layer 2: xs2b = bf16(dinv * (h1b @ W2)); pruned gather + concat -> cB ----
    k_gemm2bf<<<(N + 63) / 64, 256, 0, stream>>>(h1b, W2, dinv, xs2b, N);
    k_gather_pairs<<<(B + 1) / 2, 256, 0, stream>>>(rowstart, csr, dinv, xs2b, b2, ui, ii, cB, B);

    // ---- fused MLP ----
    k_mlp<<<B / 64, 256, 0, stream>>>(cB, fcW1, fcb1, g1, be1,
                                      fcW2, fcb2, g2, be2, fcW3, fcb3, out);
}

// Round 8
// 432.991 us; speedup vs baseline: 1.4712x; 1.1144x over previous
//
#include <hip/hip_runtime.h>
#include <hip/hip_bf16.h>
#include <math.h>

#define N_USERS_C 100000
#define BK_SHIFT 9
#define BK_NODES 512

__device__ __forceinline__ unsigned int pack_bf16(float a, float b) {
    __hip_bfloat16 ha = __float2bfloat16(a), hb = __float2bfloat16(b);
    return ((unsigned int)(*(unsigned short*)&hb) << 16) | (unsigned int)(*(unsigned short*)&ha);
}
__device__ __forceinline__ float bf_lo(unsigned int u) { return __uint_as_float(u << 16); }
__device__ __forceinline__ float bf_hi(unsigned int u) { return __uint_as_float(u & 0xffff0000u); }

// ---------------- zero 512 ints (1 block, 512 thr) ----------------
__global__ __launch_bounds__(512) void k_zero512(int* __restrict__ p) {
    p[threadIdx.x] = 0;
}

// ---------------- merged: bucket histogram (blocks < EB) || x->bf16 (rest) ----------------
__global__ __launch_bounds__(512) void k_pre(const int* __restrict__ dst, int* __restrict__ chist,
                                             const float* __restrict__ x, unsigned int* __restrict__ xb,
                                             int E, int nbk, int EB, int n2) {
    __shared__ int lcnt[BK_NODES];
    const int bid = blockIdx.x;
    const int t = threadIdx.x;
    if (bid < EB) {
        for (int i = t; i < nbk; i += 512) lcnt[i] = 0;
        __syncthreads();
        int e0 = bid * 2048;
        #pragma unroll
        for (int j = 0; j < 4; ++j) {
            int e = e0 + j * 512 + t;
            if (e < E) atomicAdd(&lcnt[dst[e] >> BK_SHIFT], 1);
        }
        __syncthreads();
        for (int i = t; i < nbk; i += 512)
            if (lcnt[i]) atomicAdd(&chist[i], lcnt[i]);
    } else {
        int base = (bid - EB) * 2048;
        #pragma unroll
        for (int j = 0; j < 4; ++j) {
            int i = base + j * 512 + t;
            if (i < n2) {
                float2 v = ((const float2*)x)[i];
                xb[i] = pack_bf16(v.x, v.y);
            }
        }
    }
}

// ---------------- scan buckets -> bucketBase, cursor; rowstart[N]=E ----------------
__global__ __launch_bounds__(512) void k_scanChist(const int* __restrict__ chist,
                                                   int* __restrict__ base,
                                                   int* __restrict__ cursor,
                                                   int* __restrict__ rowstart,
                                                   int nbk, int N, int E) {
    __shared__ int s[512];
    int t = threadIdx.x;
    int v = (t < nbk) ? chist[t] : 0;
    s[t] = v;
    __syncthreads();
    for (int off = 1; off < 512; off <<= 1) {
        int u = (t >= off) ? s[t - off] : 0;
        __syncthreads();
        s[t] += u;
        __syncthreads();
    }
    int ex = s[t] - v;
    if (t < nbk) { base[t] = ex; cursor[t] = ex; }
    if (t == 0) { base[nbk] = E; rowstart[N] = E; }
}

// ---------------- pass 1: block-local counting sort into bucket regions ----------------
__global__ __launch_bounds__(512) void k_bin(const int* __restrict__ src,
                                             const int* __restrict__ dst,
                                             int* __restrict__ bucketCursor,
                                             int* __restrict__ pairBuf, int E, int nbk) {
    __shared__ int lcnt[BK_NODES];
    __shared__ int scanS[512];
    __shared__ int lofs[BK_NODES];
    __shared__ int delta[BK_NODES];
    __shared__ int sPack[2048];
    __shared__ unsigned short sBkt[2048];
    int t = threadIdx.x;
    int e0 = blockIdx.x * 2048;
    for (int i = t; i < nbk; i += 512) lcnt[i] = 0;
    __syncthreads();

    int mySrc[4], myB[4], myDl[4];
    #pragma unroll
    for (int j = 0; j < 4; ++j) {
        int e = e0 + j * 512 + t;
        if (e < E) {
            int sv = src[e], dv = dst[e];
            mySrc[j] = sv; myB[j] = dv >> BK_SHIFT; myDl[j] = dv & (BK_NODES - 1);
            atomicAdd(&lcnt[myB[j]], 1);
        } else myB[j] = -1;
    }
    __syncthreads();
    int v = (t < nbk) ? lcnt[t] : 0;
    scanS[t] = v;
    __syncthreads();
    for (int off = 1; off < 512; off <<= 1) {
        int u = (t >= off) ? scanS[t - off] : 0;
        __syncthreads();
        scanS[t] += u;
        __syncthreads();
    }
    if (t < nbk) lofs[t] = scanS[t] - v;
    __syncthreads();
    if (t < nbk) {
        int c = lcnt[t];
        int gb = (c > 0) ? atomicAdd(&bucketCursor[t], c) : 0;
        delta[t] = gb - lofs[t];
    }
    __syncthreads();
    #pragma unroll
    for (int j = 0; j < 4; ++j) {
        if (myB[j] >= 0) {
            int p = atomicAdd(&lofs[myB[j]], 1);
            sPack[p] = mySrc[j] | (myDl[j] << 18);   // src < 2^18
            sBkt[p] = (unsigned short)myB[j];
        }
    }
    __syncthreads();
    int total = (E - e0 < 2048) ? (E - e0) : 2048;
    for (int i = t; i < total; i += 512)
        pairBuf[delta[sBkt[i]] + i] = sPack[i];
}

// ---------------- pass 2: per-bucket node hist/scan -> rowstart,dinv; scatter csr ----------------
__global__ __launch_bounds__(256) void k_bscatter(const int* __restrict__ pairBuf,
                                                  const int* __restrict__ base,
                                                  int* __restrict__ rowstart,
                                                  float* __restrict__ dinv,
                                                  int* __restrict__ csr, int N) {
    int b = blockIdx.x;
    int n0 = b << BK_SHIFT;
    int n1 = n0 + BK_NODES; if (n1 > N) n1 = N;
    int nn = n1 - n0;
    __shared__ int hist[BK_NODES];
    __shared__ int curs[BK_NODES];
    __shared__ int ps[256];
    int t = threadIdx.x;
    for (int i = t; i < nn; i += 256) hist[i] = 0;
    __syncthreads();
    int e0 = base[b], e1 = base[b + 1];
    for (int e = e0 + t; e < e1; e += 256)
        atomicAdd(&hist[pairBuf[e] >> 18], 1);
    __syncthreads();
    int h0 = (2 * t < nn) ? hist[2 * t] : 0;
    int h1 = (2 * t + 1 < nn) ? hist[2 * t + 1] : 0;
    int p = h0 + h1;
    ps[t] = p;
    __syncthreads();
    for (int off = 1; off < 256; off <<= 1) {
        int u = (t >= off) ? ps[t - off] : 0;
        __syncthreads();
        ps[t] += u;
        __syncthreads();
    }
    int ex = ps[t] - p;
    if (2 * t < nn) {
        int r0 = e0 + ex;
        rowstart[n0 + 2 * t] = r0; curs[2 * t] = r0;
        dinv[n0 + 2 * t] = rsqrtf((float)(h0 + 1));
    }
    if (2 * t + 1 < nn) {
        int r1 = e0 + ex + h0;
        rowstart[n0 + 2 * t + 1] = r1; curs[2 * t + 1] = r1;
        dinv[n0 + 2 * t + 1] = rsqrtf((float)(h1 + 1));
    }
    __syncthreads();
    for (int e = e0 + t; e < e1; e += 256) {
        int pk = pairBuf[e];
        int pos = atomicAdd(&curs[pk >> 18], 1);
        csr[pos] = pk & 0x3FFFF;
    }
}

// ---------------- gather1 v2: aggXb = bf16(A_hat x); dwordx4 loads, 8 edges/instr ----------------
// lane l: sub=l>>3 (edge within group of 8), c=l&7 (16B chunk = features 8c..8c+7)
__global__ __launch_bounds__(256) void k_gather1(const int* __restrict__ rowstart,
                                                 const int* __restrict__ csr,
                                                 const float* __restrict__ dinv,
                                                 const uint4* __restrict__ xb4,
                                                 const float* __restrict__ x,
                                                 unsigned int* __restrict__ outb, int N) {
    const int node = blockIdx.x * 4 + (threadIdx.x >> 6);
    const int l = threadIdx.x & 63;
    if (node >= N) return;
    const int sub = l >> 3;
    const int c = l & 7;
    const int rs = rowstart[node];
    const int re = rowstart[node + 1];

    float acc[8] = {0.f, 0.f, 0.f, 0.f, 0.f, 0.f, 0.f, 0.f};
    for (int base = rs; base < re; base += 64) {
        int idx = base + l;
        int sE = (idx < re) ? csr[idx] : 0;
        float dE = (idx < re) ? dinv[sE] : 0.0f;   // 0 => no contribution
        int cnt = re - base; if (cnt > 64) cnt = 64;
        int groups = (cnt + 7) >> 3;
        for (int g = 0; g < groups; ++g) {
            int e = g * 8 + sub;
            int sk = __shfl(sE, e);
            float dk = __shfl(dE, e);
            uint4 u = xb4[(size_t)sk * 8 + c];
            acc[0] += dk * bf_lo(u.x); acc[1] += dk * bf_hi(u.x);
            acc[2] += dk * bf_lo(u.y); acc[3] += dk * bf_hi(u.y);
            acc[4] += dk * bf_lo(u.z); acc[5] += dk * bf_hi(u.z);
            acc[6] += dk * bf_lo(u.w); acc[7] += dk * bf_hi(u.w);
        }
    }
    #pragma unroll
    for (int m = 8; m < 64; m <<= 1)
        #pragma unroll
        for (int i = 0; i < 8; ++i) acc[i] += __shfl_xor(acc[i], m);
    if (sub == 0) {   // lanes 0..7, c = lane: features 8c..8c+7
        float dd = dinv[node];
        float d2 = dd * dd;
        float4 x0 = ((const float4*)x)[(size_t)node * 16 + c * 2];
        float4 x1 = ((const float4*)x)[(size_t)node * 16 + c * 2 + 1];
        uint4 o;
        o.x = pack_bf16(dd * acc[0] + d2 * x0.x, dd * acc[1] + d2 * x0.y);
        o.y = pack_bf16(dd * acc[2] + d2 * x0.z, dd * acc[3] + d2 * x0.w);
        o.z = pack_bf16(dd * acc[4] + d2 * x1.x, dd * acc[5] + d2 * x1.y);
        o.w = pack_bf16(dd * acc[6] + d2 * x1.z, dd * acc[7] + d2 * x1.w);
        ((uint4*)outb)[(size_t)node * 8 + c] = o;
    }
}

// ---------------- fused layer1+layer2: xs2b = bf16(dinv*(relu(aggX@W1+b1)@W2)) ----------------
// Block 256 thr, 64 rows. h1 tile lives only in LDS (bf16, stride 66 uints).
__global__ __launch_bounds__(256) void k_layer12(const unsigned int* __restrict__ aggXb,
                                                 const float* __restrict__ W1,
                                                 const float* __restrict__ b1,
                                                 const float* __restrict__ W2,
                                                 const float* __restrict__ dinv,
                                                 unsigned int* __restrict__ xs2b, int N) {
    __shared__ float sX[64 * 68];     // phase1: aggX f32 (ld 68); phase2: h1 bf16 (ld 66 uints)
    __shared__ float sW[64 * 128];    // W1 f32, then W2 f32
    unsigned int* sH = (unsigned int*)sX;
    const int t = threadIdx.x;
    const int row0 = blockIdx.x * 64;
    const int rg = t >> 4;
    const int cg = t & 15;

    // stage aggX (unpack bf16 -> f32)
    for (int i = t; i < 512; i += 256) {
        int r = i >> 3, c = i & 7;
        int row = row0 + r;
        uint4 u = (row < N) ? ((const uint4*)aggXb)[(size_t)row * 8 + c]
                            : make_uint4(0u, 0u, 0u, 0u);
        float4 f0, f1;
        f0.x = bf_lo(u.x); f0.y = bf_hi(u.x); f0.z = bf_lo(u.y); f0.w = bf_hi(u.y);
        f1.x = bf_lo(u.z); f1.y = bf_hi(u.z); f1.z = bf_lo(u.w); f1.w = bf_hi(u.w);
        *(float4*)&sX[r * 68 + c * 8] = f0;
        *(float4*)&sX[r * 68 + c * 8 + 4] = f1;
    }
    // stage W1 (64x128)
    for (int i = t; i < 2048; i += 256) {
        int k = i >> 5, c4 = i & 31;
        *(float4*)&sW[k * 128 + c4 * 4] = *(const float4*)&W1[k * 128 + c4 * 4];
    }
    __syncthreads();

    // phase 1: h1 = aggX @ W1 + b1 (64x128, K=64)
    float acc1[4][8];
    {
        float4 b01 = *(const float4*)&b1[cg * 8];
        float4 b23 = *(const float4*)&b1[cg * 8 + 4];
        #pragma unroll
        for (int jj = 0; jj < 4; ++jj) {
            acc1[jj][0] = b01.x; acc1[jj][1] = b01.y; acc1[jj][2] = b01.z; acc1[jj][3] = b01.w;
            acc1[jj][4] = b23.x; acc1[jj][5] = b23.y; acc1[jj][6] = b23.z; acc1[jj][7] = b23.w;
        }
    }
    for (int k0 = 0; k0 < 64; k0 += 4) {
        float4 a[4];
        #pragma unroll
        for (int jj = 0; jj < 4; ++jj) a[jj] = *(const float4*)&sX[(rg * 4 + jj) * 68 + k0];
        #pragma unroll
        for (int kk = 0; kk < 4; ++kk) {
            float4 w0 = *(const float4*)&sW[(k0 + kk) * 128 + cg * 8];
            float4 w1 = *(const float4*)&sW[(k0 + kk) * 128 + cg * 8 + 4];
            #pragma unroll
            for (int jj = 0; jj < 4; ++jj) {
                float f = ((const float*)&a[jj])[kk];
                acc1[jj][0] += f * w0.x; acc1[jj][1] += f * w0.y;
                acc1[jj][2] += f * w0.z; acc1[jj][3] += f * w0.w;
                acc1[jj][4] += f * w1.x; acc1[jj][5] += f * w1.y;
                acc1[jj][6] += f * w1.z; acc1[jj][7] += f * w1.w;
            }
        }
    }
    __syncthreads();   // all reads of sX (aggX) and sW (W1) complete

    // write relu(h1) as bf16 into sH; stage W2 into sW
    #pragma unroll
    for (int jj = 0; jj < 4; ++jj) {
        int r = rg * 4 + jj;
        #pragma unroll
        for (int q = 0; q < 4; ++q)
            sH[r * 66 + cg * 4 + q] =
                pack_bf16(fmaxf(acc1[jj][2 * q], 0.f), fmaxf(acc1[jj][2 * q + 1], 0.f));
    }
    for (int i = t; i < 2048; i += 256) {
        int k = i >> 4, c4 = i & 15;
        *(float4*)&sW[k * 64 + c4 * 4] = *(const float4*)&W2[k * 64 + c4 * 4];
    }
    __syncthreads();

    // phase 2: xs2 = h1 @ W2 (64x64, K=128), scale by dinv, pack bf16
    float acc2[4][4];
    #pragma unroll
    for (int jj = 0; jj < 4; ++jj)
        #pragma unroll
        for (int cc = 0; cc < 4; ++cc) acc2[jj][cc] = 0.0f;

    for (int k0 = 0; k0 < 128; k0 += 4) {
        float4 w[4];
        #pragma unroll
        for (int kk = 0; kk < 4; ++kk) w[kk] = *(const float4*)&sW[(k0 + kk) * 64 + cg * 4];
        #pragma unroll
        for (int jj = 0; jj < 4; ++jj) {
            uint2 hu = *(const uint2*)&sH[(rg * 4 + jj) * 66 + (k0 >> 1)];
            float a[4] = {bf_lo(hu.x), bf_hi(hu.x), bf_lo(hu.y), bf_hi(hu.y)};
            #pragma unroll
            for (int kk = 0; kk < 4; ++kk) {
                float f = a[kk];
                acc2[jj][0] += f * w[kk].x; acc2[jj][1] += f * w[kk].y;
                acc2[jj][2] += f * w[kk].z; acc2[jj][3] += f * w[kk].w;
            }
        }
    }
    #pragma unroll
    for (int jj = 0; jj < 4; ++jj) {
        int row = row0 + rg * 4 + jj;
        if (row < N) {
            float sc = dinv[row];
            uint2 o;
            o.x = pack_bf16(acc2[jj][0] * sc, acc2[jj][1] * sc);
            o.y = pack_bf16(acc2[jj][2] * sc, acc2[jj][3] * sc);
            ((uint2*)xs2b)[(size_t)row * 16 + cg] = o;
        }
    }
}

// ---------------- gather_pairs v2 (dwordx4 loads): cB[b] = [h2(u), h2(i)] ----------------
__global__ __launch_bounds__(256) void k_gather_pairs(const int* __restrict__ rowstart,
                                                      const int* __restrict__ csr,
                                                      const float* __restrict__ dinv,
                                                      const uint4* __restrict__ xs2b4,
                                                      const float* __restrict__ b2,
                                                      const int* __restrict__ ui,
                                                      const int* __restrict__ ii,
                                                      float* __restrict__ cB, int B) {
    const int wave = threadIdx.x >> 6;
    const int b = blockIdx.x * 2 + (wave >> 1);
    const int half = wave & 1;   // 0=user, 1=item
    const int l = threadIdx.x & 63;
    const int sub = l >> 3;
    const int c = l & 7;
    if (b >= B) return;
    const int node = (half == 0) ? (ui[b] - 1) : (N_USERS_C + ii[b] - 1);
    const int rs = rowstart[node];
    const int re = rowstart[node + 1];

    float acc[8] = {0.f, 0.f, 0.f, 0.f, 0.f, 0.f, 0.f, 0.f};
    for (int base = rs; base < re; base += 64) {
        int idx = base + l;
        int sE = (idx < re) ? csr[idx] : 0;
        float vE = (idx < re) ? 1.0f : 0.0f;
        int cnt = re - base; if (cnt > 64) cnt = 64;
        int groups = (cnt + 7) >> 3;
        for (int g = 0; g < groups; ++g) {
            int e = g * 8 + sub;
            int sk = __shfl(sE, e);
            float vk = __shfl(vE, e);
            uint4 u = xs2b4[(size_t)sk * 8 + c];
            acc[0] += vk * bf_lo(u.x); acc[1] += vk * bf_hi(u.x);
            acc[2] += vk * bf_lo(u.y); acc[3] += vk * bf_hi(u.y);
            acc[4] += vk * bf_lo(u.z); acc[5] += vk * bf_hi(u.z);
            acc[6] += vk * bf_lo(u.w); acc[7] += vk * bf_hi(u.w);
        }
    }
    #pragma unroll
    for (int m = 8; m < 64; m <<= 1)
        #pragma unroll
        for (int i = 0; i < 8; ++i) acc[i] += __shfl_xor(acc[i], m);
    if (sub == 0) {   // lanes 0..7: features 8c..8c+7
        float dd = dinv[node];
        uint4 us = xs2b4[(size_t)node * 8 + c];
        float4 s0, s1;
        s0.x = bf_lo(us.x); s0.y = bf_hi(us.x); s0.z = bf_lo(us.y); s0.w = bf_hi(us.y);
        s1.x = bf_lo(us.z); s1.y = bf_hi(us.z); s1.z = bf_lo(us.w); s1.w = bf_hi(us.w);
        float4 bb0 = ((const float4*)b2)[c * 2];
        float4 bb1 = ((const float4*)b2)[c * 2 + 1];
        float4 o0, o1;
        o0.x = dd * (acc[0] + s0.x) + bb0.x;
        o0.y = dd * (acc[1] + s0.y) + bb0.y;
        o0.z = dd * (acc[2] + s0.z) + bb0.z;
        o0.w = dd * (acc[3] + s0.w) + bb0.w;
        o1.x = dd * (acc[4] + s1.x) + bb1.x;
        o1.y = dd * (acc[5] + s1.y) + bb1.y;
        o1.z = dd * (acc[6] + s1.z) + bb1.z;
        o1.w = dd * (acc[7] + s1.w) + bb1.w;
        ((float4*)cB)[(size_t)b * 32 + half * 16 + c * 2] = o0;
        ((float4*)cB)[(size_t)b * 32 + half * 16 + c * 2 + 1] = o1;
    }
}

// ---------------- fused MLP: fc1+LN+ReLU+fc2+LN+ReLU+fc3+sigmoid ----------------
__global__ __launch_bounds__(256) void k_mlp(const float* __restrict__ cB,
                                             const float* __restrict__ fcW1, const float* __restrict__ fcb1,
                                             const float* __restrict__ g1,   const float* __restrict__ be1,
                                             const float* __restrict__ fcW2, const float* __restrict__ fcb2,
                                             const float* __restrict__ g2,   const float* __restrict__ be2,
                                             const float* __restrict__ fcW3, const float* __restrict__ fcb3,
                                             float* __restrict__ out) {
    __shared__ float sIn[64 * 128];
    __shared__ float sW[64 * 128];
    const int t = threadIdx.x;
    const int row0 = blockIdx.x * 64;
    const int rg = t >> 4;
    const int cg = t & 15;

    for (int i = t; i < 2048; i += 256) {
        int r = i >> 5, c4 = i & 31;
        *(float4*)&sIn[r * 128 + c4 * 4] = *(const float4*)&cB[(size_t)(row0 + r) * 128 + c4 * 4];
    }

    float acc1[4][8];
    {
        float4 b01 = *(const float4*)&fcb1[cg * 8];
        float4 b23 = *(const float4*)&fcb1[cg * 8 + 4];
        #pragma unroll
        for (int jj = 0; jj < 4; ++jj) {
            acc1[jj][0] = b01.x; acc1[jj][1] = b01.y; acc1[jj][2] = b01.z; acc1[jj][3] = b01.w;
            acc1[jj][4] = b23.x; acc1[jj][5] = b23.y; acc1[jj][6] = b23.z; acc1[jj][7] = b23.w;
        }
    }
    for (int s = 0; s < 2; ++s) {
        __syncthreads();
        for (int i = t; i < 2048; i += 256) {
            int k = i >> 5, c4 = i & 31;
            *(float4*)&sW[k * 128 + c4 * 4] = *(const float4*)&fcW1[(size_t)(64 * s + k) * 128 + c4 * 4];
        }
        __syncthreads();
        for (int k0 = 0; k0 < 64; k0 += 4) {
            float4 a[4];
            #pragma unroll
            for (int jj = 0; jj < 4; ++jj)
                a[jj] = *(const float4*)&sIn[(rg * 4 + jj) * 128 + 64 * s + k0];
            #pragma unroll
            for (int kk = 0; kk < 4; ++kk) {
                float4 w0 = *(const float4*)&sW[(k0 + kk) * 128 + cg * 8];
                float4 w1 = *(const float4*)&sW[(k0 + kk) * 128 + cg * 8 + 4];
                #pragma unroll
                for (int jj = 0; jj < 4; ++jj) {
                    float f = ((const float*)&a[jj])[kk];
                    acc1[jj][0] += f * w0.x; acc1[jj][1] += f * w0.y;
                    acc1[jj][2] += f * w0.z; acc1[jj][3] += f * w0.w;
                    acc1[jj][4] += f * w1.x; acc1[jj][5] += f * w1.y;
                    acc1[jj][6] += f * w1.z; acc1[jj][7] += f * w1.w;
                }
            }
        }
    }
    __syncthreads();

    {
        float4 g01 = *(const float4*)&g1[cg * 8];
        float4 g23 = *(const float4*)&g1[cg * 8 + 4];
        float4 e01 = *(const float4*)&be1[cg * 8];
        float4 e23 = *(const float4*)&be1[cg * 8 + 4];
        float gv[8] = {g01.x, g01.y, g01.z, g01.w, g23.x, g23.y, g23.z, g23.w};
        float ev[8] = {e01.x, e01.y, e01.z, e01.w, e23.x, e23.y, e23.z, e23.w};
        #pragma unroll
        for (int jj = 0; jj < 4; ++jj) {
            float s_ = 0.f, ss = 0.f;
            #pragma unroll
            for (int c = 0; c < 8; ++c) { float v = acc1[jj][c]; s_ += v; ss += v * v; }
            #pragma unroll
            for (int m = 1; m < 16; m <<= 1) { s_ += __shfl_xor(s_, m); ss += __shfl_xor(ss, m); }
            float mu = s_ * (1.0f / 128.0f);
            float var = ss * (1.0f / 128.0f) - mu * mu;
            float rs = rsqrtf(var + 1e-5f);
            #pragma unroll
            for (int c = 0; c < 8; ++c) {
                float z = (acc1[jj][c] - mu) * rs * gv[c] + ev[c];
                sIn[(rg * 4 + jj) * 128 + cg * 8 + c] = fmaxf(z, 0.f);
            }
        }
    }
    __syncthreads();

    for (int i = t; i < 2048; i += 256) {
        int k = i >> 4, c4 = i & 15;
        *(float4*)&sW[k * 64 + c4 * 4] = *(const float4*)&fcW2[(size_t)k * 64 + c4 * 4];
    }
    float acc2[4][4];
    {
        float4 bv = *(const float4*)&fcb2[cg * 4];
        #pragma unroll
        for (int jj = 0; jj < 4; ++jj) {
            acc2[jj][0] = bv.x; acc2[jj][1] = bv.y; acc2[jj][2] = bv.z; acc2[jj][3] = bv.w;
        }
    }
    __syncthreads();
    for (int k0 = 0; k0 < 128; k0 += 4) {
        float4 a[4], w[4];
        #pragma unroll
        for (int jj = 0; jj < 4; ++jj) a[jj] = *(const float4*)&sIn[(rg * 4 + jj) * 128 + k0];
        #pragma unroll
        for (int kk = 0; kk < 4; ++kk) w[kk] = *(const float4*)&sW[(k0 + kk) * 64 + cg * 4];
        #pragma unroll
        for (int jj = 0; jj < 4; ++jj) {
            const float* aj = (const float*)&a[jj];
            #pragma unroll
            for (int kk = 0; kk < 4; ++kk) {
                float f = aj[kk];
                acc2[jj][0] += f * w[kk].x; acc2[jj][1] += f * w[kk].y;
                acc2[jj][2] += f * w[kk].z; acc2[jj][3] += f * w[kk].w;
            }
        }
    }

    {
        float4 gv4 = *(const float4*)&g2[cg * 4];
        float4 ev4 = *(const float4*)&be2[cg * 4];
        float4 w34 = *(const float4*)&fcW3[cg * 4];
        float gv[4] = {gv4.x, gv4.y, gv4.z, gv4.w};
        float ev[4] = {ev4.x, ev4.y, ev4.z, ev4.w};
        float wv[4] = {w34.x, w34.y, w34.z, w34.w};
        float b3 = fcb3[0];
        #pragma unroll
        for (int jj = 0; jj < 4; ++jj) {
            float s_ = 0.f, ss = 0.f;
            #pragma unroll
            for (int c = 0; c < 4; ++c) { float v = acc2[jj][c]; s_ += v; ss += v * v; }
            #pragma unroll
            for (int m = 1; m < 16; m <<= 1) { s_ += __shfl_xor(s_, m); ss += __shfl_xor(ss, m); }
            float mu = s_ * (1.0f / 64.0f);
            float var = ss * (1.0f / 64.0f) - mu * mu;
            float rs = rsqrtf(var + 1e-5f);
            float p = 0.f;
            #pragma unroll
            for (int c = 0; c < 4; ++c) {
                float z = fmaxf((acc2[jj][c] - mu) * rs * gv[c] + ev[c], 0.f);
                p += z * wv[c];
            }
            #pragma unroll
            for (int m = 1; m < 16; m <<= 1) p += __shfl_xor(p, m);
            if (cg == 0) out[row0 + rg * 4 + jj] = 1.0f / (1.0f + expf(-(p + b3)));
        }
    }
}

extern "C" void kernel_launch(void* const* d_in, const int* in_sizes, int n_in,
                              void* d_out, int out_size, void* d_ws, size_t ws_size,
                              hipStream_t stream) {
    const float* x    = (const float*)d_in[0];
    const int*   src  = (const int*)d_in[1];
    const int*   dst  = (const int*)d_in[2];
    const int*   ui   = (const int*)d_in[3];
    const int*   ii   = (const int*)d_in[4];
    const float* W1   = (const float*)d_in[5];
    const float* b1   = (const float*)d_in[6];
    const float* W2   = (const float*)d_in[7];
    const float* b2   = (const float*)d_in[8];
    const float* fcW1 = (const float*)d_in[9];
    const float* fcb1 = (const float*)d_in[10];
    const float* g1   = (const float*)d_in[11];
    const float* be1  = (const float*)d_in[12];
    const float* fcW2 = (const float*)d_in[13];
    const float* fcb2 = (const float*)d_in[14];
    const float* g2   = (const float*)d_in[15];
    const float* be2  = (const float*)d_in[16];
    const float* fcW3 = (const float*)d_in[17];
    const float* fcb3 = (const float*)d_in[18];
    float* out = (float*)d_out;

    const int N = in_sizes[0] / 64;          // 150000
    const int E = in_sizes[1];               // 2400000
    const int B = in_sizes[3];               // 16384
    const int NBK = (N + BK_NODES - 1) >> BK_SHIFT;   // 293
    const int EB = (E + 2047) / 2048;        // 1172
    const int n2 = N * 32;                   // uint-pairs in x
    const int XB = (n2 + 2047) / 2048;       // 2344+

    // ---- workspace layout (~77 MB) ----
    float* ws   = (float*)d_ws;
    float* dinv = ws;                                   // N
    int* rowstart = (int*)(dinv + N);                   // N+1
    int* csr      = rowstart + (N + 1);                 // E
    unsigned int* xb = (unsigned int*)(csr + E);        // N*32 (bf16 x)
    unsigned int* bufU = xb + (size_t)N * 32;           // N*32: CSR scratch, then aggXb
    unsigned int* xs2b = bufU + (size_t)N * 32;         // N*32 (bf16 xs2)
    float* cB = (float*)(xs2b + (size_t)N * 32);        // B*128 f32
    // CSR-build scratch aliased inside bufU (dead before aggXb written)
    int* pairBuf = (int*)bufU;                          // E
    int* chist   = pairBuf + E;                         // 512
    int* bbase   = chist + 512;                         // 513
    int* bcursor = bbase + 513;                         // 512
    unsigned int* aggXb = bufU;                         // N*32 (bf16 aggX)

    // ---- CSR build + bf16 conversion ----
    k_zero512<<<1, 512, 0, stream>>>(chist);
    k_pre<<<EB + XB, 512, 0, stream>>>(dst, chist, x, xb, E, NBK, EB, n2);
    k_scanChist<<<1, 512, 0, stream>>>(chist, bbase, bcursor, rowstart, NBK, N, E);
    k_bin<<<EB, 512, 0, stream>>>(src, dst, bcursor, pairBuf, E, NBK);
    k_bscatter<<<NBK, 256, 0, stream>>>(pairBuf, bbase, rowstart, dinv, csr, N);

    // ---- layer 1 gather: aggXb = bf16(A_hat x) ----
    k_gather1<<<(N + 3) / 4, 256, 0, stream>>>(rowstart, csr, dinv, (const uint4*)xb, x, aggXb, N);

    // ---- fused layer1 GEMM + layer2 GEMM: xs2b = bf16(dinv*(relu(aggX@W1+b1)@W2)) ----
    k_layer12<<<(N + 63) / 64, 256, 0, stream>>>(aggXb, W1, b1, W2, dinv, xs2b, N);

    // ---- pruned gather2 + concat -> cB ----
    k_gather_pairs<<<(B + 1) / 2, 256, 0, stream>>>(rowstart, csr, dinv, (const uint4*)xs2b,
                                                    b2, ui, ii, cB, B);

    // ---- fused MLP ----
    k_mlp<<<B / 64, 256, 0, stream>>>(cB, fcW1, fcb1, g1, be1,
                                      fcW2, fcb2, g2, be2, fcW3, fcb3, out);
}

// Round 9
// 387.414 us; speedup vs baseline: 1.6443x; 1.1176x over previous
//
#include <hip/hip_runtime.h>
#include <hip/hip_bf16.h>
#include <math.h>

#define N_USERS_C 100000
#define BK_SHIFT 9
#define BK_NODES 512

typedef __bf16 bf8_t __attribute__((ext_vector_type(8)));
typedef float f32x4 __attribute__((ext_vector_type(4)));

__device__ __forceinline__ unsigned int pack_bf16(float a, float b) {
    __hip_bfloat16 ha = __float2bfloat16(a), hb = __float2bfloat16(b);
    return ((unsigned int)(*(unsigned short*)&hb) << 16) | (unsigned int)(*(unsigned short*)&ha);
}
__device__ __forceinline__ unsigned short bf16_1(float a) {
    __hip_bfloat16 ha = __float2bfloat16(a);
    return *(unsigned short*)&ha;
}
__device__ __forceinline__ float bf_lo(unsigned int u) { return __uint_as_float(u << 16); }
__device__ __forceinline__ float bf_hi(unsigned int u) { return __uint_as_float(u & 0xffff0000u); }

// ---------------- merged: bucket histogram (blocks < EB) || x->bf16 (rest) ----------------
__global__ __launch_bounds__(512) void k_pre(const int* __restrict__ dst, int* __restrict__ chist,
                                             const float* __restrict__ x, unsigned int* __restrict__ xb,
                                             int E, int nbk, int EB, int n2) {
    __shared__ int lcnt[BK_NODES];
    const int bid = blockIdx.x;
    const int t = threadIdx.x;
    if (bid < EB) {
        for (int i = t; i < nbk; i += 512) lcnt[i] = 0;
        __syncthreads();
        int e0 = bid * 2048;
        #pragma unroll
        for (int j = 0; j < 4; ++j) {
            int e = e0 + j * 512 + t;
            if (e < E) atomicAdd(&lcnt[dst[e] >> BK_SHIFT], 1);
        }
        __syncthreads();
        for (int i = t; i < nbk; i += 512)
            if (lcnt[i]) atomicAdd(&chist[i], lcnt[i]);
    } else {
        int base = (bid - EB) * 2048;
        #pragma unroll
        for (int j = 0; j < 4; ++j) {
            int i = base + j * 512 + t;
            if (i < n2) {
                float2 v = ((const float2*)x)[i];
                xb[i] = pack_bf16(v.x, v.y);
            }
        }
    }
}

// ---------------- scan buckets -> bucketBase, cursor; rowstart[N]=E ----------------
__global__ __launch_bounds__(512) void k_scanChist(const int* __restrict__ chist,
                                                   int* __restrict__ base,
                                                   int* __restrict__ cursor,
                                                   int* __restrict__ rowstart,
                                                   int nbk, int N, int E) {
    __shared__ int s[512];
    int t = threadIdx.x;
    int v = (t < nbk) ? chist[t] : 0;
    s[t] = v;
    __syncthreads();
    for (int off = 1; off < 512; off <<= 1) {
        int u = (t >= off) ? s[t - off] : 0;
        __syncthreads();
        s[t] += u;
        __syncthreads();
    }
    int ex = s[t] - v;
    if (t < nbk) { base[t] = ex; cursor[t] = ex; }
    if (t == 0) { base[nbk] = E; rowstart[N] = E; }
}

// ---------------- pass 1: block-local counting sort into bucket regions ----------------
__global__ __launch_bounds__(512) void k_bin(const int* __restrict__ src,
                                             const int* __restrict__ dst,
                                             int* __restrict__ bucketCursor,
                                             int* __restrict__ pairBuf, int E, int nbk) {
    __shared__ int lcnt[BK_NODES];
    __shared__ int scanS[512];
    __shared__ int lofs[BK_NODES];
    __shared__ int delta[BK_NODES];
    __shared__ int sPack[2048];
    __shared__ unsigned short sBkt[2048];
    int t = threadIdx.x;
    int e0 = blockIdx.x * 2048;
    for (int i = t; i < nbk; i += 512) lcnt[i] = 0;
    __syncthreads();

    int mySrc[4], myB[4], myDl[4];
    #pragma unroll
    for (int j = 0; j < 4; ++j) {
        int e = e0 + j * 512 + t;
        if (e < E) {
            int sv = src[e], dv = dst[e];
            mySrc[j] = sv; myB[j] = dv >> BK_SHIFT; myDl[j] = dv & (BK_NODES - 1);
            atomicAdd(&lcnt[myB[j]], 1);
        } else myB[j] = -1;
    }
    __syncthreads();
    int v = (t < nbk) ? lcnt[t] : 0;
    scanS[t] = v;
    __syncthreads();
    for (int off = 1; off < 512; off <<= 1) {
        int u = (t >= off) ? scanS[t - off] : 0;
        __syncthreads();
        scanS[t] += u;
        __syncthreads();
    }
    if (t < nbk) lofs[t] = scanS[t] - v;
    __syncthreads();
    if (t < nbk) {
        int c = lcnt[t];
        int gb = (c > 0) ? atomicAdd(&bucketCursor[t], c) : 0;
        delta[t] = gb - lofs[t];
    }
    __syncthreads();
    #pragma unroll
    for (int j = 0; j < 4; ++j) {
        if (myB[j] >= 0) {
            int p = atomicAdd(&lofs[myB[j]], 1);
            sPack[p] = mySrc[j] | (myDl[j] << 18);   // src < 2^18
            sBkt[p] = (unsigned short)myB[j];
        }
    }
    __syncthreads();
    int total = (E - e0 < 2048) ? (E - e0) : 2048;
    for (int i = t; i < total; i += 512)
        pairBuf[delta[sBkt[i]] + i] = sPack[i];
}

// ---------------- pass 2: per-bucket node hist/scan -> rowstart,dinv; scatter csr ----------------
__global__ __launch_bounds__(256) void k_bscatter(const int* __restrict__ pairBuf,
                                                  const int* __restrict__ base,
                                                  int* __restrict__ rowstart,
                                                  float* __restrict__ dinv,
                                                  int* __restrict__ csr, int N) {
    int b = blockIdx.x;
    int n0 = b << BK_SHIFT;
    int n1 = n0 + BK_NODES; if (n1 > N) n1 = N;
    int nn = n1 - n0;
    __shared__ int hist[BK_NODES];
    __shared__ int curs[BK_NODES];
    __shared__ int ps[256];
    int t = threadIdx.x;
    for (int i = t; i < nn; i += 256) hist[i] = 0;
    __syncthreads();
    int e0 = base[b], e1 = base[b + 1];
    for (int e = e0 + t; e < e1; e += 256)
        atomicAdd(&hist[pairBuf[e] >> 18], 1);
    __syncthreads();
    int h0 = (2 * t < nn) ? hist[2 * t] : 0;
    int h1 = (2 * t + 1 < nn) ? hist[2 * t + 1] : 0;
    int p = h0 + h1;
    ps[t] = p;
    __syncthreads();
    for (int off = 1; off < 256; off <<= 1) {
        int u = (t >= off) ? ps[t - off] : 0;
        __syncthreads();
        ps[t] += u;
        __syncthreads();
    }
    int ex = ps[t] - p;
    if (2 * t < nn) {
        int r0 = e0 + ex;
        rowstart[n0 + 2 * t] = r0; curs[2 * t] = r0;
        dinv[n0 + 2 * t] = rsqrtf((float)(h0 + 1));
    }
    if (2 * t + 1 < nn) {
        int r1 = e0 + ex + h0;
        rowstart[n0 + 2 * t + 1] = r1; curs[2 * t + 1] = r1;
        dinv[n0 + 2 * t + 1] = rsqrtf((float)(h1 + 1));
    }
    __syncthreads();
    for (int e = e0 + t; e < e1; e += 256) {
        int pk = pairBuf[e];
        int pos = atomicAdd(&curs[pk >> 18], 1);
        csr[pos] = pk & 0x3FFFF;
    }
}

// ---------------- gather1: aggXb = bf16(A_hat x); dwordx4 loads, 8 edges/instr ----------------
__global__ __launch_bounds__(256) void k_gather1(const int* __restrict__ rowstart,
                                                 const int* __restrict__ csr,
                                                 const float* __restrict__ dinv,
                                                 const uint4* __restrict__ xb4,
                                                 const float* __restrict__ x,
                                                 unsigned int* __restrict__ outb, int N) {
    const int node = blockIdx.x * 4 + (threadIdx.x >> 6);
    const int l = threadIdx.x & 63;
    if (node >= N) return;
    const int sub = l >> 3;
    const int c = l & 7;
    const int rs = rowstart[node];
    const int re = rowstart[node + 1];

    float acc[8] = {0.f, 0.f, 0.f, 0.f, 0.f, 0.f, 0.f, 0.f};
    for (int base = rs; base < re; base += 64) {
        int idx = base + l;
        int sE = (idx < re) ? csr[idx] : 0;
        float dE = (idx < re) ? dinv[sE] : 0.0f;
        int cnt = re - base; if (cnt > 64) cnt = 64;
        int groups = (cnt + 7) >> 3;
        for (int g = 0; g < groups; ++g) {
            int e = g * 8 + sub;
            int sk = __shfl(sE, e);
            float dk = __shfl(dE, e);
            uint4 u = xb4[(size_t)sk * 8 + c];
            acc[0] += dk * bf_lo(u.x); acc[1] += dk * bf_hi(u.x);
            acc[2] += dk * bf_lo(u.y); acc[3] += dk * bf_hi(u.y);
            acc[4] += dk * bf_lo(u.z); acc[5] += dk * bf_hi(u.z);
            acc[6] += dk * bf_lo(u.w); acc[7] += dk * bf_hi(u.w);
        }
    }
    #pragma unroll
    for (int m = 8; m < 64; m <<= 1)
        #pragma unroll
        for (int i = 0; i < 8; ++i) acc[i] += __shfl_xor(acc[i], m);
    if (sub == 0) {
        float dd = dinv[node];
        float d2 = dd * dd;
        float4 x0 = ((const float4*)x)[(size_t)node * 16 + c * 2];
        float4 x1 = ((const float4*)x)[(size_t)node * 16 + c * 2 + 1];
        uint4 o;
        o.x = pack_bf16(dd * acc[0] + d2 * x0.x, dd * acc[1] + d2 * x0.y);
        o.y = pack_bf16(dd * acc[2] + d2 * x0.z, dd * acc[3] + d2 * x0.w);
        o.z = pack_bf16(dd * acc[4] + d2 * x1.x, dd * acc[5] + d2 * x1.y);
        o.w = pack_bf16(dd * acc[6] + d2 * x1.z, dd * acc[7] + d2 * x1.w);
        ((uint4*)outb)[(size_t)node * 8 + c] = o;
    }
}

// ---------------- fused layer1+layer2 via MFMA bf16 ----------------
// Block 256 thr (4 waves), 64 rows. wave w owns M-tile w (16 rows).
// Phase1: C1[64x128] = aggX[64x64] @ W1 (16 MFMAs/wave); h1=relu(C1+b1) -> LDS bf16.
// Phase2: C2[64x64] = h1[64x128] @ W2 (16 MFMAs/wave); xs2b = bf16(dinv*C2).
// MFMA 16x16x32 layouts (verified m89/m120): A row=lane&15,k=quad*8+j; B col=lane&15,
// k=quad*8+j; C/D col=lane&15,row=quad*4+reg.
__global__ __launch_bounds__(256) void k_layer12(const unsigned int* __restrict__ aggXb,
                                                 const float* __restrict__ W1,
                                                 const float* __restrict__ b1,
                                                 const float* __restrict__ W2,
                                                 const float* __restrict__ dinv,
                                                 unsigned int* __restrict__ xs2b, int N) {
    __shared__ unsigned int sA[64 * 36];    // aggX bf16 (stride 36 uints); later C2 out-stage
    __shared__ unsigned int sB[128 * 36];   // W1T bf16 (stride 36); later W2T bf16 (stride 68)
    __shared__ unsigned int sC[64 * 68];    // h1 bf16 (stride 68 uints = 136 bf16)
    const int t = threadIdx.x;
    const int w = t >> 6;
    const int l = t & 63;
    const int n16 = l & 15;
    const int quad = l >> 4;
    const int row0 = blockIdx.x * 64;

    // stage aggX rows (bf16-packed, 8 uint4/row)
    for (int i = t; i < 512; i += 256) {
        int r = i >> 3, c = i & 7;
        int row = row0 + r;
        uint4 u = (row < N) ? ((const uint4*)aggXb)[(size_t)row * 8 + c]
                            : make_uint4(0u, 0u, 0u, 0u);
        *(uint4*)&sA[r * 36 + c * 4] = u;
    }
    // stage W1T bf16: W1[k=64][n=128] -> sB[n*36 + k/2]  (coalesced reads over n)
    for (int i = t; i < 4096; i += 256) {
        int kp = i >> 7, n = i & 127;
        float a0 = W1[(size_t)(2 * kp) * 128 + n];
        float a1 = W1[(size_t)(2 * kp + 1) * 128 + n];
        sB[n * 36 + kp] = pack_bf16(a0, a1);
    }
    __syncthreads();

    // phase 1
    f32x4 acc[8];
    #pragma unroll
    for (int nt = 0; nt < 8; ++nt) acc[nt] = (f32x4){0.f, 0.f, 0.f, 0.f};
    {
        const int am = w * 16 + n16;
        bf8_t a0 = *(const bf8_t*)&sA[am * 36 + quad * 4];
        bf8_t a1 = *(const bf8_t*)&sA[am * 36 + 16 + quad * 4];
        #pragma unroll
        for (int nt = 0; nt < 8; ++nt) {
            bf8_t b0 = *(const bf8_t*)&sB[(nt * 16 + n16) * 36 + quad * 4];
            bf8_t b1v = *(const bf8_t*)&sB[(nt * 16 + n16) * 36 + 16 + quad * 4];
            acc[nt] = __builtin_amdgcn_mfma_f32_16x16x32_bf16(a0, b0, acc[nt], 0, 0, 0);
            acc[nt] = __builtin_amdgcn_mfma_f32_16x16x32_bf16(a1, b1v, acc[nt], 0, 0, 0);
        }
    }
    __syncthreads();   // all phase-1 reads of sA/sB done

    // h1 = relu(C1 + b1) -> sC (bf16, u16 scatter); stage W2T into sB (stride 68)
    {
        unsigned short* sC16 = (unsigned short*)sC;
        #pragma unroll
        for (int nt = 0; nt < 8; ++nt) {
            int col = nt * 16 + n16;
            float bv = b1[col];
            #pragma unroll
            for (int reg = 0; reg < 4; ++reg) {
                int r = w * 16 + quad * 4 + reg;
                sC16[r * 136 + col] = bf16_1(fmaxf(acc[nt][reg] + bv, 0.f));
            }
        }
    }
    for (int i = t; i < 4096; i += 256) {
        int kp = i >> 6, n = i & 63;
        float a0 = W2[(size_t)(2 * kp) * 64 + n];
        float a1 = W2[(size_t)(2 * kp + 1) * 64 + n];
        sB[n * 68 + kp] = pack_bf16(a0, a1);
    }
    __syncthreads();

    // phase 2
    f32x4 acc2[4];
    #pragma unroll
    for (int nt = 0; nt < 4; ++nt) acc2[nt] = (f32x4){0.f, 0.f, 0.f, 0.f};
    {
        const int am = w * 16 + n16;
        #pragma unroll
        for (int ks = 0; ks < 4; ++ks) {
            bf8_t a = *(const bf8_t*)&sC[am * 68 + ks * 16 + quad * 4];
            #pragma unroll
            for (int nt = 0; nt < 4; ++nt) {
                bf8_t b = *(const bf8_t*)&sB[(nt * 16 + n16) * 68 + ks * 16 + quad * 4];
                acc2[nt] = __builtin_amdgcn_mfma_f32_16x16x32_bf16(a, b, acc2[nt], 0, 0, 0);
            }
        }
    }

    // epilogue: xs2 = dinv*C2, bf16 -> sA (stride 36 uints = 72 shorts), then packed copy-out
    {
        unsigned short* sA16 = (unsigned short*)sA;
        #pragma unroll
        for (int reg = 0; reg < 4; ++reg) {
            int r = w * 16 + quad * 4 + reg;
            int row = row0 + r;
            float dd = (row < N) ? dinv[row] : 0.f;
            #pragma unroll
            for (int nt = 0; nt < 4; ++nt)
                sA16[r * 72 + nt * 16 + n16] = bf16_1(acc2[nt][reg] * dd);
        }
    }
    __syncthreads();
    for (int i = t; i < 512; i += 256) {
        int r = i >> 3, c = i & 7;
        int row = row0 + r;
        if (row < N)
            ((uint4*)xs2b)[(size_t)row * 8 + c] = *(uint4*)&sA[r * 36 + c * 4];
    }
}

// ---------------- gather_pairs (dwordx4 loads): cB[b] = [h2(u), h2(i)] ----------------
__global__ __launch_bounds__(256) void k_gather_pairs(const int* __restrict__ rowstart,
                                                      const int* __restrict__ csr,
                                                      const float* __restrict__ dinv,
                                                      const uint4* __restrict__ xs2b4,
                                                      const float* __restrict__ b2,
                                                      const int* __restrict__ ui,
                                                      const int* __restrict__ ii,
                                                      float* __restrict__ cB, int B) {
    const int wave = threadIdx.x >> 6;
    const int b = blockIdx.x * 2 + (wave >> 1);
    const int half = wave & 1;
    const int l = threadIdx.x & 63;
    const int sub = l >> 3;
    const int c = l & 7;
    if (b >= B) return;
    const int node = (half == 0) ? (ui[b] - 1) : (N_USERS_C + ii[b] - 1);
    const int rs = rowstart[node];
    const int re = rowstart[node + 1];

    float acc[8] = {0.f, 0.f, 0.f, 0.f, 0.f, 0.f, 0.f, 0.f};
    for (int base = rs; base < re; base += 64) {
        int idx = base + l;
        int sE = (idx < re) ? csr[idx] : 0;
        float vE = (idx < re) ? 1.0f : 0.0f;
        int cnt = re - base; if (cnt > 64) cnt = 64;
        int groups = (cnt + 7) >> 3;
        for (int g = 0; g < groups; ++g) {
            int e = g * 8 + sub;
            int sk = __shfl(sE, e);
            float vk = __shfl(vE, e);
            uint4 u = xs2b4[(size_t)sk * 8 + c];
            acc[0] += vk * bf_lo(u.x); acc[1] += vk * bf_hi(u.x);
            acc[2] += vk * bf_lo(u.y); acc[3] += vk * bf_hi(u.y);
            acc[4] += vk * bf_lo(u.z); acc[5] += vk * bf_hi(u.z);
            acc[6] += vk * bf_lo(u.w); acc[7] += vk * bf_hi(u.w);
        }
    }
    #pragma unroll
    for (int m = 8; m < 64; m <<= 1)
        #pragma unroll
        for (int i = 0; i < 8; ++i) acc[i] += __shfl_xor(acc[i], m);
    if (sub == 0) {
        float dd = dinv[node];
        uint4 us = xs2b4[(size_t)node * 8 + c];
        float4 s0, s1;
        s0.x = bf_lo(us.x); s0.y = bf_hi(us.x); s0.z = bf_lo(us.y); s0.w = bf_hi(us.y);
        s1.x = bf_lo(us.z); s1.y = bf_hi(us.z); s1.z = bf_lo(us.w); s1.w = bf_hi(us.w);
        float4 bb0 = ((const float4*)b2)[c * 2];
        float4 bb1 = ((const float4*)b2)[c * 2 + 1];
        float4 o0, o1;
        o0.x = dd * (acc[0] + s0.x) + bb0.x;
        o0.y = dd * (acc[1] + s0.y) + bb0.y;
        o0.z = dd * (acc[2] + s0.z) + bb0.z;
        o0.w = dd * (acc[3] + s0.w) + bb0.w;
        o1.x = dd * (acc[4] + s1.x) + bb1.x;
        o1.y = dd * (acc[5] + s1.y) + bb1.y;
        o1.z = dd * (acc[6] + s1.z) + bb1.z;
        o1.w = dd * (acc[7] + s1.w) + bb1.w;
        ((float4*)cB)[(size_t)b * 32 + half * 16 + c * 2] = o0;
        ((float4*)cB)[(size_t)b * 32 + half * 16 + c * 2 + 1] = o1;
    }
}

// ---------------- fused MLP: 32 rows/block (512 blocks, better tail) ----------------
__global__ __launch_bounds__(256) void k_mlp(const float* __restrict__ cB,
                                             const float* __restrict__ fcW1, const float* __restrict__ fcb1,
                                             const float* __restrict__ g1,   const float* __restrict__ be1,
                                             const float* __restrict__ fcW2, const float* __restrict__ fcb2,
                                             const float* __restrict__ g2,   const float* __restrict__ be2,
                                             const float* __restrict__ fcW3, const float* __restrict__ fcb3,
                                             float* __restrict__ out) {
    __shared__ float sIn[32 * 128];
    __shared__ float sW[64 * 128];
    const int t = threadIdx.x;
    const int row0 = blockIdx.x * 32;
    const int rg = t >> 4;     // 0..15, 2 rows each
    const int cg = t & 15;

    for (int i = t; i < 1024; i += 256) {
        int r = i >> 5, c4 = i & 31;
        *(float4*)&sIn[r * 128 + c4 * 4] = *(const float4*)&cB[(size_t)(row0 + r) * 128 + c4 * 4];
    }

    float acc1[2][8];
    {
        float4 b01 = *(const float4*)&fcb1[cg * 8];
        float4 b23 = *(const float4*)&fcb1[cg * 8 + 4];
        #pragma unroll
        for (int jj = 0; jj < 2; ++jj) {
            acc1[jj][0] = b01.x; acc1[jj][1] = b01.y; acc1[jj][2] = b01.z; acc1[jj][3] = b01.w;
            acc1[jj][4] = b23.x; acc1[jj][5] = b23.y; acc1[jj][6] = b23.z; acc1[jj][7] = b23.w;
        }
    }
    for (int s = 0; s < 2; ++s) {
        __syncthreads();
        for (int i = t; i < 2048; i += 256) {
            int k = i >> 5, c4 = i & 31;
            *(float4*)&sW[k * 128 + c4 * 4] = *(const float4*)&fcW1[(size_t)(64 * s + k) * 128 + c4 * 4];
        }
        __syncthreads();
        for (int k0 = 0; k0 < 64; k0 += 4) {
            float4 a[2];
            #pragma unroll
            for (int jj = 0; jj < 2; ++jj)
                a[jj] = *(const float4*)&sIn[(rg * 2 + jj) * 128 + 64 * s + k0];
            #pragma unroll
            for (int kk = 0; kk < 4; ++kk) {
                float4 w0 = *(const float4*)&sW[(k0 + kk) * 128 + cg * 8];
                float4 w1 = *(const float4*)&sW[(k0 + kk) * 128 + cg * 8 + 4];
                #pragma unroll
                for (int jj = 0; jj < 2; ++jj) {
                    float f = ((const float*)&a[jj])[kk];
                    acc1[jj][0] += f * w0.x; acc1[jj][1] += f * w0.y;
                    acc1[jj][2] += f * w0.z; acc1[jj][3] += f * w0.w;
                    acc1[jj][4] += f * w1.x; acc1[jj][5] += f * w1.y;
                    acc1[jj][6] += f * w1.z; acc1[jj][7] += f * w1.w;
                }
            }
        }
    }
    __syncthreads();

    {
        float4 g01 = *(const float4*)&g1[cg * 8];
        float4 g23 = *(const float4*)&g1[cg * 8 + 4];
        float4 e01 = *(const float4*)&be1[cg * 8];
        float4 e23 = *(const float4*)&be1[cg * 8 + 4];
        float gv[8] = {g01.x, g01.y, g01.z, g01.w, g23.x, g23.y, g23.z, g23.w};
        float ev[8] = {e01.x, e01.y, e01.z, e01.w, e23.x, e23.y, e23.z, e23.w};
        #pragma unroll
        for (int jj = 0; jj < 2; ++jj) {
            float s_ = 0.f, ss = 0.f;
            #pragma unroll
            for (int c = 0; c < 8; ++c) { float v = acc1[jj][c]; s_ += v; ss += v * v; }
            #pragma unroll
            for (int m = 1; m < 16; m <<= 1) { s_ += __shfl_xor(s_, m); ss += __shfl_xor(ss, m); }
            float mu = s_ * (1.0f / 128.0f);
            float var = ss * (1.0f / 128.0f) - mu * mu;
            float rs = rsqrtf(var + 1e-5f);
            #pragma unroll
            for (int c = 0; c < 8; ++c) {
                float z = (acc1[jj][c] - mu) * rs * gv[c] + ev[c];
                sIn[(rg * 2 + jj) * 128 + cg * 8 + c] = fmaxf(z, 0.f);
            }
        }
    }
    __syncthreads();

    for (int i = t; i < 2048; i += 256) {
        int k = i >> 4, c4 = i & 15;
        *(float4*)&sW[k * 64 + c4 * 4] = *(const float4*)&fcW2[(size_t)k * 64 + c4 * 4];
    }
    float acc2[2][4];
    {
        float4 bv = *(const float4*)&fcb2[cg * 4];
        #pragma unroll
        for (int jj = 0; jj < 2; ++jj) {
            acc2[jj][0] = bv.x; acc2[jj][1] = bv.y; acc2[jj][2] = bv.z; acc2[jj][3] = bv.w;
        }
    }
    __syncthreads();
    for (int k0 = 0; k0 < 128; k0 += 4) {
        float4 a[2], w[4];
        #pragma unroll
        for (int jj = 0; jj < 2; ++jj) a[jj] = *(const float4*)&sIn[(rg * 2 + jj) * 128 + k0];
        #pragma unroll
        for (int kk = 0; kk < 4; ++kk) w[kk] = *(const float4*)&sW[(k0 + kk) * 64 + cg * 4];
        #pragma unroll
        for (int jj = 0; jj < 2; ++jj) {
            const float* aj = (const float*)&a[jj];
            #pragma unroll
            for (int kk = 0; kk < 4; ++kk) {
                float f = aj[kk];
                acc2[jj][0] += f * w[kk].x; acc2[jj][1] += f * w[kk].y;
                acc2[jj][2] += f * w[kk].z; acc2[jj][3] += f * w[kk].w;
            }
        }
    }

    {
        float4 gv4 = *(const float4*)&g2[cg * 4];
        float4 ev4 = *(const float4*)&be2[cg * 4];
        float4 w34 = *(const float4*)&fcW3[cg * 4];
        float gv[4] = {gv4.x, gv4.y, gv4.z, gv4.w};
        float ev[4] = {ev4.x, ev4.y, ev4.z, ev4.w};
        float wv[4] = {w34.x, w34.y, w34.z, w34.w};
        float b3 = fcb3[0];
        #pragma unroll
        for (int jj = 0; jj < 2; ++jj) {
            float s_ = 0.f, ss = 0.f;
            #pragma unroll
            for (int c = 0; c < 4; ++c) { float v = acc2[jj][c]; s_ += v; ss += v * v; }
            #pragma unroll
            for (int m = 1; m < 16; m <<= 1) { s_ += __shfl_xor(s_, m); ss += __shfl_xor(ss, m); }
            float mu = s_ * (1.0f / 64.0f);
            float var = ss * (1.0f / 64.0f) - mu * mu;
            float rs = rsqrtf(var + 1e-5f);
            float p = 0.f;
            #pragma unroll
            for (int c = 0; c < 4; ++c) {
                float z = fmaxf((acc2[jj][c] - mu) * rs * gv[c] + ev[c], 0.f);
                p += z * wv[c];
            }
            #pragma unroll
            for (int m = 1; m < 16; m <<= 1) p += __shfl_xor(p, m);
            if (cg == 0) out[row0 + rg * 2 + jj] = 1.0f / (1.0f + expf(-(p + b3)));
        }
    }
}

extern "C" void kernel_launch(void* const* d_in, const int* in_sizes, int n_in,
                              void* d_out, int out_size, void* d_ws, size_t ws_size,
                              hipStream_t stream) {
    const float* x    = (const float*)d_in[0];
    const int*   src  = (const int*)d_in[1];
    const int*   dst  = (const int*)d_in[2];
    const int*   ui   = (const int*)d_in[3];
    const int*   ii   = (const int*)d_in[4];
    const float* W1   = (const float*)d_in[5];
    const float* b1   = (const float*)d_in[6];
    const float* W2   = (const float*)d_in[7];
    const float* b2   = (const float*)d_in[8];
    const float* fcW1 = (const float*)d_in[9];
    const float* fcb1 = (const float*)d_in[10];
    const float* g1   = (const float*)d_in[11];
    const float* be1  = (const float*)d_in[12];
    const float* fcW2 = (const float*)d_in[13];
    const float* fcb2 = (const float*)d_in[14];
    const float* g2   = (const float*)d_in[15];
    const float* be2  = (const float*)d_in[16];
    const float* fcW3 = (const float*)d_in[17];
    const float* fcb3 = (const float*)d_in[18];
    float* out = (float*)d_out;

    const int N = in_sizes[0] / 64;          // 150000
    const int E = in_sizes[1];               // 2400000
    const int B = in_sizes[3];               // 16384
    const int NBK = (N + BK_NODES - 1) >> BK_SHIFT;   // 293
    const int EB = (E + 2047) / 2048;        // 1172
    const int n2 = N * 32;
    const int XB = (n2 + 2047) / 2048;

    // ---- workspace layout (~77 MB) ----
    float* ws   = (float*)d_ws;
    float* dinv = ws;                                   // N
    int* rowstart = (int*)(dinv + N);                   // N+1
    int* csr      = rowstart + (N + 1);                 // E
    unsigned int* xb = (unsigned int*)(csr + E);        // N*32 (bf16 x)
    unsigned int* bufU = xb + (size_t)N * 32;           // N*32: CSR scratch, then aggXb
    unsigned int* xs2b = bufU + (size_t)N * 32;         // N*32 (bf16 xs2)
    float* cB = (float*)(xs2b + (size_t)N * 32);        // B*128 f32
    int* pairBuf = (int*)bufU;                          // E
    int* chist   = pairBuf + E;                         // 512
    int* bbase   = chist + 512;                         // 513
    int* bcursor = bbase + 513;                         // 512
    unsigned int* aggXb = bufU;                         // N*32 (bf16 aggX)

    // ---- CSR build + bf16 conversion ----
    hipMemsetAsync(chist, 0, 512 * sizeof(int), stream);
    k_pre<<<EB + XB, 512, 0, stream>>>(dst, chist, x, xb, E, NBK, EB, n2);
    k_scanChist<<<1, 512, 0, stream>>>(chist, bbase, bcursor, rowstart, NBK, N, E);
    k_bin<<<EB, 512, 0, stream>>>(src, dst, bcursor, pairBuf, E, NBK);
    k_bscatter<<<NBK, 256, 0, stream>>>(pairBuf, bbase, rowstart, dinv, csr, N);

    // ---- layer 1 gather ----
    k_gather1<<<(N + 3) / 4, 256, 0, stream>>>(rowstart, csr, dinv, (const uint4*)xb, x, aggXb, N);

    // ---- fused layer1+layer2 GEMMs (MFMA bf16) ----
    k_layer12<<<(N + 63) / 64, 256, 0, stream>>>(aggXb, W1, b1, W2, dinv, xs2b, N);

    // ---- pruned gather2 + concat ----
    k_gather_pairs<<<(B + 1) / 2, 256, 0, stream>>>(rowstart, csr, dinv, (const uint4*)xs2b,
                                                    b2, ui, ii, cB, B);

    // ---- fused MLP ----
    k_mlp<<<B / 32, 256, 0, stream>>>(cB, fcW1, fcb1, g1, be1,
                                      fcW2, fcb2, g2, be2, fcW3, fcb3, out);
}

// Round 10
// 361.941 us; speedup vs baseline: 1.7600x; 1.0704x over previous
//
#include <hip/hip_runtime.h>
#include <hip/hip_bf16.h>
#include <math.h>

#define N_USERS_C 100000
#define BK_SHIFT 9
#define BK_NODES 512

typedef __bf16 bf8_t __attribute__((ext_vector_type(8)));
typedef float f32x4 __attribute__((ext_vector_type(4)));

__device__ __forceinline__ unsigned int pack_bf16(float a, float b) {
    __hip_bfloat16 ha = __float2bfloat16(a), hb = __float2bfloat16(b);
    return ((unsigned int)(*(unsigned short*)&hb) << 16) | (unsigned int)(*(unsigned short*)&ha);
}
__device__ __forceinline__ unsigned short bf16_1(float a) {
    __hip_bfloat16 ha = __float2bfloat16(a);
    return *(unsigned short*)&ha;
}
__device__ __forceinline__ float bf_lo(unsigned int u) { return __uint_as_float(u << 16); }
__device__ __forceinline__ float bf_hi(unsigned int u) { return __uint_as_float(u & 0xffff0000u); }

// ---------------- merged: bucket histogram (4096 edges/blk) || x->bf16 ----------------
__global__ __launch_bounds__(512) void k_pre(const int* __restrict__ dst, int* __restrict__ chist,
                                             const float* __restrict__ x, unsigned int* __restrict__ xb,
                                             int E, int nbk, int EB2, int n2) {
    __shared__ int lcnt[BK_NODES];
    const int bid = blockIdx.x;
    const int t = threadIdx.x;
    if (bid < EB2) {
        if (t < nbk) lcnt[t] = 0;
        __syncthreads();
        int e0 = bid * 4096;
        #pragma unroll
        for (int j = 0; j < 8; ++j) {
            int e = e0 + j * 512 + t;
            if (e < E) atomicAdd(&lcnt[dst[e] >> BK_SHIFT], 1);
        }
        __syncthreads();
        if (t < nbk && lcnt[t]) atomicAdd(&chist[t], lcnt[t]);
    } else {
        int base = (bid - EB2) * 2048;
        #pragma unroll
        for (int j = 0; j < 4; ++j) {
            int i = base + j * 512 + t;
            if (i < n2) {
                float2 v = ((const float2*)x)[i];
                xb[i] = pack_bf16(v.x, v.y);
            }
        }
    }
}

// ---------------- scan buckets -> bucketBase, cursor; rowstart[N]=E ----------------
__global__ __launch_bounds__(512) void k_scanChist(const int* __restrict__ chist,
                                                   int* __restrict__ base,
                                                   int* __restrict__ cursor,
                                                   int* __restrict__ rowstart,
                                                   int nbk, int N, int E) {
    __shared__ int s[512];
    int t = threadIdx.x;
    int v = (t < nbk) ? chist[t] : 0;
    s[t] = v;
    __syncthreads();
    for (int off = 1; off < 512; off <<= 1) {
        int u = (t >= off) ? s[t - off] : 0;
        __syncthreads();
        s[t] += u;
        __syncthreads();
    }
    int ex = s[t] - v;
    if (t < nbk) { base[t] = ex; cursor[t] = ex; }
    if (t == 0) { base[nbk] = E; rowstart[N] = E; }
}

// ---------------- pass 1: block-local counting sort (wave-shuffle scans) ----------------
__global__ __launch_bounds__(512) void k_bin(const int* __restrict__ src,
                                             const int* __restrict__ dst,
                                             int* __restrict__ bucketCursor,
                                             int* __restrict__ pairBuf, int E, int nbk) {
    __shared__ int lcnt[BK_NODES];
    __shared__ int lofs[BK_NODES];
    __shared__ int delta[BK_NODES];
    __shared__ int waveSum[8];
    __shared__ int sPack[2048];
    __shared__ unsigned short sBkt[2048];
    const int t = threadIdx.x;
    const int lane = t & 63;
    const int w = t >> 6;
    const int e0 = blockIdx.x * 2048;
    if (t < nbk) lcnt[t] = 0;
    __syncthreads();

    int mySrc[4], myB[4], myDl[4];
    #pragma unroll
    for (int j = 0; j < 4; ++j) {
        int e = e0 + j * 512 + t;
        if (e < E) {
            int sv = src[e], dv = dst[e];
            mySrc[j] = sv; myB[j] = dv >> BK_SHIFT; myDl[j] = dv & (BK_NODES - 1);
            atomicAdd(&lcnt[myB[j]], 1);
        } else myB[j] = -1;
    }
    __syncthreads();

    // wave-shuffle exclusive scan over lcnt[0..nbk)
    int v = (t < nbk) ? lcnt[t] : 0;
    int inc = v;
    #pragma unroll
    for (int off = 1; off < 64; off <<= 1) {
        int n = __shfl_up(inc, off);
        if (lane >= off) inc += n;
    }
    if (lane == 63) waveSum[w] = inc;
    __syncthreads();
    int wp = 0;
    #pragma unroll
    for (int i = 0; i < 8; ++i) wp += (i < w) ? waveSum[i] : 0;
    int ex = wp + inc - v;   // exclusive prefix
    if (t < nbk) {
        lofs[t] = ex;
        int gb = (v > 0) ? atomicAdd(&bucketCursor[t], v) : 0;
        delta[t] = gb - ex;
    }
    __syncthreads();

    // place into LDS ordered by bucket
    #pragma unroll
    for (int j = 0; j < 4; ++j) {
        if (myB[j] >= 0) {
            int p = atomicAdd(&lofs[myB[j]], 1);
            sPack[p] = mySrc[j] | (myDl[j] << 18);   // src < 2^18
            sBkt[p] = (unsigned short)myB[j];
        }
    }
    __syncthreads();
    int total = (E - e0 < 2048) ? (E - e0) : 2048;
    for (int i = t; i < total; i += 512)
        pairBuf[delta[sBkt[i]] + i] = sPack[i];
}

// ---------------- pass 2 (512 thr, 1 node/thread): rowstart,dinv; scatter csr ----------------
__global__ __launch_bounds__(512) void k_bscatter(const int* __restrict__ pairBuf,
                                                  const int* __restrict__ base,
                                                  int* __restrict__ rowstart,
                                                  float* __restrict__ dinv,
                                                  int* __restrict__ csr, int N) {
    const int b = blockIdx.x;
    const int n0 = b << BK_SHIFT;
    int nn = N - n0; if (nn > BK_NODES) nn = BK_NODES;
    __shared__ int hist[BK_NODES];
    __shared__ int curs[BK_NODES];
    __shared__ int waveSum[8];
    const int t = threadIdx.x;
    const int lane = t & 63;
    const int w = t >> 6;
    if (t < nn) hist[t] = 0;
    __syncthreads();
    const int e0 = base[b], e1 = base[b + 1];
    for (int e = e0 + t; e < e1; e += 512)
        atomicAdd(&hist[pairBuf[e] >> 18], 1);
    __syncthreads();

    int v = (t < nn) ? hist[t] : 0;
    int inc = v;
    #pragma unroll
    for (int off = 1; off < 64; off <<= 1) {
        int n = __shfl_up(inc, off);
        if (lane >= off) inc += n;
    }
    if (lane == 63) waveSum[w] = inc;
    __syncthreads();
    int wp = 0;
    #pragma unroll
    for (int i = 0; i < 8; ++i) wp += (i < w) ? waveSum[i] : 0;
    int ex = wp + inc - v;
    if (t < nn) {
        int r = e0 + ex;
        rowstart[n0 + t] = r;
        curs[t] = r;
        dinv[n0 + t] = rsqrtf((float)(v + 1));
    }
    __syncthreads();
    for (int e = e0 + t; e < e1; e += 512) {
        int pk = pairBuf[e];
        int pos = atomicAdd(&curs[pk >> 18], 1);
        csr[pos] = pk & 0x3FFFF;
    }
}

// ---------------- gather1: aggXb = bf16(A_hat x); dwordx4 loads, 8 edges/instr ----------------
__global__ __launch_bounds__(256) void k_gather1(const int* __restrict__ rowstart,
                                                 const int* __restrict__ csr,
                                                 const float* __restrict__ dinv,
                                                 const uint4* __restrict__ xb4,
                                                 const float* __restrict__ x,
                                                 unsigned int* __restrict__ outb, int N) {
    const int node = blockIdx.x * 4 + (threadIdx.x >> 6);
    const int l = threadIdx.x & 63;
    if (node >= N) return;
    const int sub = l >> 3;
    const int c = l & 7;
    const int rs = rowstart[node];
    const int re = rowstart[node + 1];

    float acc[8] = {0.f, 0.f, 0.f, 0.f, 0.f, 0.f, 0.f, 0.f};
    for (int base = rs; base < re; base += 64) {
        int idx = base + l;
        int sE = (idx < re) ? csr[idx] : 0;
        float dE = (idx < re) ? dinv[sE] : 0.0f;
        int cnt = re - base; if (cnt > 64) cnt = 64;
        int groups = (cnt + 7) >> 3;
        for (int g = 0; g < groups; ++g) {
            int e = g * 8 + sub;
            int sk = __shfl(sE, e);
            float dk = __shfl(dE, e);
            uint4 u = xb4[(size_t)sk * 8 + c];
            acc[0] += dk * bf_lo(u.x); acc[1] += dk * bf_hi(u.x);
            acc[2] += dk * bf_lo(u.y); acc[3] += dk * bf_hi(u.y);
            acc[4] += dk * bf_lo(u.z); acc[5] += dk * bf_hi(u.z);
            acc[6] += dk * bf_lo(u.w); acc[7] += dk * bf_hi(u.w);
        }
    }
    #pragma unroll
    for (int m = 8; m < 64; m <<= 1)
        #pragma unroll
        for (int i = 0; i < 8; ++i) acc[i] += __shfl_xor(acc[i], m);
    if (sub == 0) {
        float dd = dinv[node];
        float d2 = dd * dd;
        float4 x0 = ((const float4*)x)[(size_t)node * 16 + c * 2];
        float4 x1 = ((const float4*)x)[(size_t)node * 16 + c * 2 + 1];
        uint4 o;
        o.x = pack_bf16(dd * acc[0] + d2 * x0.x, dd * acc[1] + d2 * x0.y);
        o.y = pack_bf16(dd * acc[2] + d2 * x0.z, dd * acc[3] + d2 * x0.w);
        o.z = pack_bf16(dd * acc[4] + d2 * x1.x, dd * acc[5] + d2 * x1.y);
        o.w = pack_bf16(dd * acc[6] + d2 * x1.z, dd * acc[7] + d2 * x1.w);
        ((uint4*)outb)[(size_t)node * 8 + c] = o;
    }
}

// ---------------- fused layer1+layer2 via MFMA bf16 ----------------
__global__ __launch_bounds__(256) void k_layer12(const unsigned int* __restrict__ aggXb,
                                                 const float* __restrict__ W1,
                                                 const float* __restrict__ b1,
                                                 const float* __restrict__ W2,
                                                 const float* __restrict__ dinv,
                                                 unsigned int* __restrict__ xs2b, int N) {
    __shared__ unsigned int sA[64 * 36];    // aggX bf16; later C2 out-stage
    __shared__ unsigned int sB[128 * 36];   // W1T bf16 (stride 36); later W2T (stride 68)
    __shared__ unsigned int sC[64 * 68];    // h1 bf16 (stride 68 uints = 136 bf16)
    const int t = threadIdx.x;
    const int w = t >> 6;
    const int l = t & 63;
    const int n16 = l & 15;
    const int quad = l >> 4;
    const int row0 = blockIdx.x * 64;

    for (int i = t; i < 512; i += 256) {
        int r = i >> 3, c = i & 7;
        int row = row0 + r;
        uint4 u = (row < N) ? ((const uint4*)aggXb)[(size_t)row * 8 + c]
                            : make_uint4(0u, 0u, 0u, 0u);
        *(uint4*)&sA[r * 36 + c * 4] = u;
    }
    for (int i = t; i < 4096; i += 256) {
        int kp = i >> 7, n = i & 127;
        float a0 = W1[(size_t)(2 * kp) * 128 + n];
        float a1 = W1[(size_t)(2 * kp + 1) * 128 + n];
        sB[n * 36 + kp] = pack_bf16(a0, a1);
    }
    __syncthreads();

    f32x4 acc[8];
    #pragma unroll
    for (int nt = 0; nt < 8; ++nt) acc[nt] = (f32x4){0.f, 0.f, 0.f, 0.f};
    {
        const int am = w * 16 + n16;
        bf8_t a0 = *(const bf8_t*)&sA[am * 36 + quad * 4];
        bf8_t a1 = *(const bf8_t*)&sA[am * 36 + 16 + quad * 4];
        #pragma unroll
        for (int nt = 0; nt < 8; ++nt) {
            bf8_t b0 = *(const bf8_t*)&sB[(nt * 16 + n16) * 36 + quad * 4];
            bf8_t b1v = *(const bf8_t*)&sB[(nt * 16 + n16) * 36 + 16 + quad * 4];
            acc[nt] = __builtin_amdgcn_mfma_f32_16x16x32_bf16(a0, b0, acc[nt], 0, 0, 0);
            acc[nt] = __builtin_amdgcn_mfma_f32_16x16x32_bf16(a1, b1v, acc[nt], 0, 0, 0);
        }
    }
    __syncthreads();

    {
        unsigned short* sC16 = (unsigned short*)sC;
        #pragma unroll
        for (int nt = 0; nt < 8; ++nt) {
            int col = nt * 16 + n16;
            float bv = b1[col];
            #pragma unroll
            for (int reg = 0; reg < 4; ++reg) {
                int r = w * 16 + quad * 4 + reg;
                sC16[r * 136 + col] = bf16_1(fmaxf(acc[nt][reg] + bv, 0.f));
            }
        }
    }
    for (int i = t; i < 4096; i += 256) {
        int kp = i >> 6, n = i & 63;
        float a0 = W2[(size_t)(2 * kp) * 64 + n];
        float a1 = W2[(size_t)(2 * kp + 1) * 64 + n];
        sB[n * 68 + kp] = pack_bf16(a0, a1);
    }
    __syncthreads();

    f32x4 acc2[4];
    #pragma unroll
    for (int nt = 0; nt < 4; ++nt) acc2[nt] = (f32x4){0.f, 0.f, 0.f, 0.f};
    {
        const int am = w * 16 + n16;
        #pragma unroll
        for (int ks = 0; ks < 4; ++ks) {
            bf8_t a = *(const bf8_t*)&sC[am * 68 + ks * 16 + quad * 4];
            #pragma unroll
            for (int nt = 0; nt < 4; ++nt) {
                bf8_t b = *(const bf8_t*)&sB[(nt * 16 + n16) * 68 + ks * 16 + quad * 4];
                acc2[nt] = __builtin_amdgcn_mfma_f32_16x16x32_bf16(a, b, acc2[nt], 0, 0, 0);
            }
        }
    }

    {
        unsigned short* sA16 = (unsigned short*)sA;
        #pragma unroll
        for (int reg = 0; reg < 4; ++reg) {
            int r = w * 16 + quad * 4 + reg;
            int row = row0 + r;
            float dd = (row < N) ? dinv[row] : 0.f;
            #pragma unroll
            for (int nt = 0; nt < 4; ++nt)
                sA16[r * 72 + nt * 16 + n16] = bf16_1(acc2[nt][reg] * dd);
        }
    }
    __syncthreads();
    for (int i = t; i < 512; i += 256) {
        int r = i >> 3, c = i & 7;
        int row = row0 + r;
        if (row < N)
            ((uint4*)xs2b)[(size_t)row * 8 + c] = *(uint4*)&sA[r * 36 + c * 4];
    }
}

// ---------------- gather_pairs (dwordx4 loads): cB[b] = [h2(u), h2(i)] ----------------
__global__ __launch_bounds__(256) void k_gather_pairs(const int* __restrict__ rowstart,
                                                      const int* __restrict__ csr,
                                                      const float* __restrict__ dinv,
                                                      const uint4* __restrict__ xs2b4,
                                                      const float* __restrict__ b2,
                                                      const int* __restrict__ ui,
                                                      const int* __restrict__ ii,
                                                      float* __restrict__ cB, int B) {
    const int wave = threadIdx.x >> 6;
    const int b = blockIdx.x * 2 + (wave >> 1);
    const int half = wave & 1;
    const int l = threadIdx.x & 63;
    const int sub = l >> 3;
    const int c = l & 7;
    if (b >= B) return;
    const int node = (half == 0) ? (ui[b] - 1) : (N_USERS_C + ii[b] - 1);
    const int rs = rowstart[node];
    const int re = rowstart[node + 1];

    float acc[8] = {0.f, 0.f, 0.f, 0.f, 0.f, 0.f, 0.f, 0.f};
    for (int base = rs; base < re; base += 64) {
        int idx = base + l;
        int sE = (idx < re) ? csr[idx] : 0;
        float vE = (idx < re) ? 1.0f : 0.0f;
        int cnt = re - base; if (cnt > 64) cnt = 64;
        int groups = (cnt + 7) >> 3;
        for (int g = 0; g < groups; ++g) {
            int e = g * 8 + sub;
            int sk = __shfl(sE, e);
            float vk = __shfl(vE, e);
            uint4 u = xs2b4[(size_t)sk * 8 + c];
            acc[0] += vk * bf_lo(u.x); acc[1] += vk * bf_hi(u.x);
            acc[2] += vk * bf_lo(u.y); acc[3] += vk * bf_hi(u.y);
            acc[4] += vk * bf_lo(u.z); acc[5] += vk * bf_hi(u.z);
            acc[6] += vk * bf_lo(u.w); acc[7] += vk * bf_hi(u.w);
        }
    }
    #pragma unroll
    for (int m = 8; m < 64; m <<= 1)
        #pragma unroll
        for (int i = 0; i < 8; ++i) acc[i] += __shfl_xor(acc[i], m);
    if (sub == 0) {
        float dd = dinv[node];
        uint4 us = xs2b4[(size_t)node * 8 + c];
        float4 s0, s1;
        s0.x = bf_lo(us.x); s0.y = bf_hi(us.x); s0.z = bf_lo(us.y); s0.w = bf_hi(us.y);
        s1.x = bf_lo(us.z); s1.y = bf_hi(us.z); s1.z = bf_lo(us.w); s1.w = bf_hi(us.w);
        float4 bb0 = ((const float4*)b2)[c * 2];
        float4 bb1 = ((const float4*)b2)[c * 2 + 1];
        float4 o0, o1;
        o0.x = dd * (acc[0] + s0.x) + bb0.x;
        o0.y = dd * (acc[1] + s0.y) + bb0.y;
        o0.z = dd * (acc[2] + s0.z) + bb0.z;
        o0.w = dd * (acc[3] + s0.w) + bb0.w;
        o1.x = dd * (acc[4] + s1.x) + bb1.x;
        o1.y = dd * (acc[5] + s1.y) + bb1.y;
        o1.z = dd * (acc[6] + s1.z) + bb1.z;
        o1.w = dd * (acc[7] + s1.w) + bb1.w;
        ((float4*)cB)[(size_t)b * 32 + half * 16 + c * 2] = o0;
        ((float4*)cB)[(size_t)b * 32 + half * 16 + c * 2 + 1] = o1;
    }
}

// ---------------- fused MLP: 32 rows/block ----------------
__global__ __launch_bounds__(256) void k_mlp(const float* __restrict__ cB,
                                             const float* __restrict__ fcW1, const float* __restrict__ fcb1,
                                             const float* __restrict__ g1,   const float* __restrict__ be1,
                                             const float* __restrict__ fcW2, const float* __restrict__ fcb2,
                                             const float* __restrict__ g2,   const float* __restrict__ be2,
                                             const float* __restrict__ fcW3, const float* __restrict__ fcb3,
                                             float* __restrict__ out) {
    __shared__ float sIn[32 * 128];
    __shared__ float sW[64 * 128];
    const int t = threadIdx.x;
    const int row0 = blockIdx.x * 32;
    const int rg = t >> 4;
    const int cg = t & 15;

    for (int i = t; i < 1024; i += 256) {
        int r = i >> 5, c4 = i & 31;
        *(float4*)&sIn[r * 128 + c4 * 4] = *(const float4*)&cB[(size_t)(row0 + r) * 128 + c4 * 4];
    }

    float acc1[2][8];
    {
        float4 b01 = *(const float4*)&fcb1[cg * 8];
        float4 b23 = *(const float4*)&fcb1[cg * 8 + 4];
        #pragma unroll
        for (int jj = 0; jj < 2; ++jj) {
            acc1[jj][0] = b01.x; acc1[jj][1] = b01.y; acc1[jj][2] = b01.z; acc1[jj][3] = b01.w;
            acc1[jj][4] = b23.x; acc1[jj][5] = b23.y; acc1[jj][6] = b23.z; acc1[jj][7] = b23.w;
        }
    }
    for (int s = 0; s < 2; ++s) {
        __syncthreads();
        for (int i = t; i < 2048; i += 256) {
            int k = i >> 5, c4 = i & 31;
            *(float4*)&sW[k * 128 + c4 * 4] = *(const float4*)&fcW1[(size_t)(64 * s + k) * 128 + c4 * 4];
        }
        __syncthreads();
        for (int k0 = 0; k0 < 64; k0 += 4) {
            float4 a[2];
            #pragma unroll
            for (int jj = 0; jj < 2; ++jj)
                a[jj] = *(const float4*)&sIn[(rg * 2 + jj) * 128 + 64 * s + k0];
            #pragma unroll
            for (int kk = 0; kk < 4; ++kk) {
                float4 w0 = *(const float4*)&sW[(k0 + kk) * 128 + cg * 8];
                float4 w1 = *(const float4*)&sW[(k0 + kk) * 128 + cg * 8 + 4];
                #pragma unroll
                for (int jj = 0; jj < 2; ++jj) {
                    float f = ((const float*)&a[jj])[kk];
                    acc1[jj][0] += f * w0.x; acc1[jj][1] += f * w0.y;
                    acc1[jj][2] += f * w0.z; acc1[jj][3] += f * w0.w;
                    acc1[jj][4] += f * w1.x; acc1[jj][5] += f * w1.y;
                    acc1[jj][6] += f * w1.z; acc1[jj][7] += f * w1.w;
                }
            }
        }
    }
    __syncthreads();

    {
        float4 g01 = *(const float4*)&g1[cg * 8];
        float4 g23 = *(const float4*)&g1[cg * 8 + 4];
        float4 e01 = *(const float4*)&be1[cg * 8];
        float4 e23 = *(const float4*)&be1[cg * 8 + 4];
        float gv[8] = {g01.x, g01.y, g01.z, g01.w, g23.x, g23.y, g23.z, g23.w};
        float ev[8] = {e01.x, e01.y, e01.z, e01.w, e23.x, e23.y, e23.z, e23.w};
        #pragma unroll
        for (int jj = 0; jj < 2; ++jj) {
            float s_ = 0.f, ss = 0.f;
            #pragma unroll
            for (int c = 0; c < 8; ++c) { float v = acc1[jj][c]; s_ += v; ss += v * v; }
            #pragma unroll
            for (int m = 1; m < 16; m <<= 1) { s_ += __shfl_xor(s_, m); ss += __shfl_xor(ss, m); }
            float mu = s_ * (1.0f / 128.0f);
            float var = ss * (1.0f / 128.0f) - mu * mu;
            float rs = rsqrtf(var + 1e-5f);
            #pragma unroll
            for (int c = 0; c < 8; ++c) {
                float z = (acc1[jj][c] - mu) * rs * gv[c] + ev[c];
                sIn[(rg * 2 + jj) * 128 + cg * 8 + c] = fmaxf(z, 0.f);
            }
        }
    }
    __syncthreads();

    for (int i = t; i < 2048; i += 256) {
        int k = i >> 4, c4 = i & 15;
        *(float4*)&sW[k * 64 + c4 * 4] = *(const float4*)&fcW2[(size_t)k * 64 + c4 * 4];
    }
    float acc2[2][4];
    {
        float4 bv = *(const float4*)&fcb2[cg * 4];
        #pragma unroll
        for (int jj = 0; jj < 2; ++jj) {
            acc2[jj][0] = bv.x; acc2[jj][1] = bv.y; acc2[jj][2] = bv.z; acc2[jj][3] = bv.w;
        }
    }
    __syncthreads();
    for (int k0 = 0; k0 < 128; k0 += 4) {
        float4 a[2], w[4];
        #pragma unroll
        for (int jj = 0; jj < 2; ++jj) a[jj] = *(const float4*)&sIn[(rg * 2 + jj) * 128 + k0];
        #pragma unroll
        for (int kk = 0; kk < 4; ++kk) w[kk] = *(const float4*)&sW[(k0 + kk) * 64 + cg * 4];
        #pragma unroll
        for (int jj = 0; jj < 2; ++jj) {
            const float* aj = (const float*)&a[jj];
            #pragma unroll
            for (int kk = 0; kk < 4; ++kk) {
                float f = aj[kk];
                acc2[jj][0] += f * w[kk].x; acc2[jj][1] += f * w[kk].y;
                acc2[jj][2] += f * w[kk].z; acc2[jj][3] += f * w[kk].w;
            }
        }
    }

    {
        float4 gv4 = *(const float4*)&g2[cg * 4];
        float4 ev4 = *(const float4*)&be2[cg * 4];
        float4 w34 = *(const float4*)&fcW3[cg * 4];
        float gv[4] = {gv4.x, gv4.y, gv4.z, gv4.w};
        float ev[4] = {ev4.x, ev4.y, ev4.z, ev4.w};
        float wv[4] = {w34.x, w34.y, w34.z, w34.w};
        float b3 = fcb3[0];
        #pragma unroll
        for (int jj = 0; jj < 2; ++jj) {
            float s_ = 0.f, ss = 0.f;
            #pragma unroll
            for (int c = 0; c < 4; ++c) { float v = acc2[jj][c]; s_ += v; ss += v * v; }
            #pragma unroll
            for (int m = 1; m < 16; m <<= 1) { s_ += __shfl_xor(s_, m); ss += __shfl_xor(ss, m); }
            float mu = s_ * (1.0f / 64.0f);
            float var = ss * (1.0f / 64.0f) - mu * mu;
            float rs = rsqrtf(var + 1e-5f);
            float p = 0.f;
            #pragma unroll
            for (int c = 0; c < 4; ++c) {
                float z = fmaxf((acc2[jj][c] - mu) * rs * gv[c] + ev[c], 0.f);
                p += z * wv[c];
            }
            #pragma unroll
            for (int m = 1; m < 16; m <<= 1) p += __shfl_xor(p, m);
            if (cg == 0) out[row0 + rg * 2 + jj] = 1.0f / (1.0f + expf(-(p + b3)));
        }
    }
}

extern "C" void kernel_launch(void* const* d_in, const int* in_sizes, int n_in,
                              void* d_out, int out_size, void* d_ws, size_t ws_size,
                              hipStream_t stream) {
    const float* x    = (const float*)d_in[0];
    const int*   src  = (const int*)d_in[1];
    const int*   dst  = (const int*)d_in[2];
    const int*   ui   = (const int*)d_in[3];
    const int*   ii   = (const int*)d_in[4];
    const float* W1   = (const float*)d_in[5];
    const float* b1   = (const float*)d_in[6];
    const float* W2   = (const float*)d_in[7];
    const float* b2   = (const float*)d_in[8];
    const float* fcW1 = (const float*)d_in[9];
    const float* fcb1 = (const float*)d_in[10];
    const float* g1   = (const float*)d_in[11];
    const float* be1  = (const float*)d_in[12];
    const float* fcW2 = (const float*)d_in[13];
    const float* fcb2 = (const float*)d_in[14];
    const float* g2   = (const float*)d_in[15];
    const float* be2  = (const float*)d_in[16];
    const float* fcW3 = (const float*)d_in[17];
    const float* fcb3 = (const float*)d_in[18];
    float* out = (float*)d_out;

    const int N = in_sizes[0] / 64;          // 150000
    const int E = in_sizes[1];               // 2400000
    const int B = in_sizes[3];               // 16384
    const int NBK = (N + BK_NODES - 1) >> BK_SHIFT;   // 293
    const int EB  = (E + 2047) / 2048;       // 1172 (k_bin blocks)
    const int EB2 = (E + 4095) / 4096;       // 586  (k_pre hist blocks)
    const int n2 = N * 32;
    const int XB = (n2 + 2047) / 2048;

    // ---- workspace layout (~77 MB) ----
    float* ws   = (float*)d_ws;
    float* dinv = ws;                                   // N
    int* rowstart = (int*)(dinv + N);                   // N+1
    int* csr      = rowstart + (N + 1);                 // E
    unsigned int* xb = (unsigned int*)(csr + E);        // N*32 (bf16 x)
    unsigned int* bufU = xb + (size_t)N * 32;           // N*32: CSR scratch, then aggXb
    unsigned int* xs2b = bufU + (size_t)N * 32;         // N*32 (bf16 xs2)
    float* cB = (float*)(xs2b + (size_t)N * 32);        // B*128 f32
    int* pairBuf = (int*)bufU;                          // E
    int* chist   = pairBuf + E;                         // 512
    int* bbase   = chist + 512;                         // 513
    int* bcursor = bbase + 513;                         // 512
    unsigned int* aggXb = bufU;                         // N*32 (bf16 aggX)

    // ---- CSR build + bf16 conversion ----
    hipMemsetAsync(chist, 0, 512 * sizeof(int), stream);
    k_pre<<<EB2 + XB, 512, 0, stream>>>(dst, chist, x, xb, E, NBK, EB2, n2);
    k_scanChist<<<1, 512, 0, stream>>>(chist, bbase, bcursor, rowstart, NBK, N, E);
    k_bin<<<EB, 512, 0, stream>>>(src, dst, bcursor, pairBuf, E, NBK);
    k_bscatter<<<NBK, 512, 0, stream>>>(pairBuf, bbase, rowstart, dinv, csr, N);

    // ---- layer 1 gather ----
    k_gather1<<<(N + 3) / 4, 256, 0, stream>>>(rowstart, csr, dinv, (const uint4*)xb, x, aggXb, N);

    // ---- fused layer1+layer2 GEMMs (MFMA bf16) ----
    k_layer12<<<(N + 63) / 64, 256, 0, stream>>>(aggXb, W1, b1, W2, dinv, xs2b, N);

    // ---- pruned gather2 + concat ----
    k_gather_pairs<<<(B + 1) / 2, 256, 0, stream>>>(rowstart, csr, dinv, (const uint4*)xs2b,
                                                    b2, ui, ii, cB, B);

    // ---- fused MLP ----
    k_mlp<<<B / 32, 256, 0, stream>>>(cB, fcW1, fcb1, g1, be1,
                                      fcW2, fcb2, g2, be2, fcW3, fcb3, out);
}

// Round 11
// 345.227 us; speedup vs baseline: 1.8453x; 1.0484x over previous
//
#include <hip/hip_runtime.h>
#include <hip/hip_bf16.h>
#include <math.h>

#define N_USERS_C 100000
#define BK_SHIFT 9
#define BK_NODES 512

typedef __bf16 bf8_t __attribute__((ext_vector_type(8)));
typedef float f32x4 __attribute__((ext_vector_type(4)));

__device__ __forceinline__ unsigned int pack_bf16(float a, float b) {
    __hip_bfloat16 ha = __float2bfloat16(a), hb = __float2bfloat16(b);
    return ((unsigned int)(*(unsigned short*)&hb) << 16) | (unsigned int)(*(unsigned short*)&ha);
}
__device__ __forceinline__ unsigned short bf16_1(float a) {
    __hip_bfloat16 ha = __float2bfloat16(a);
    return *(unsigned short*)&ha;
}
__device__ __forceinline__ float bf_lo(unsigned int u) { return __uint_as_float(u << 16); }
__device__ __forceinline__ float bf_hi(unsigned int u) { return __uint_as_float(u & 0xffff0000u); }

// ---------------- merged: bucket histogram (4096 edges/blk) || x->bf16 ----------------
__global__ __launch_bounds__(512) void k_pre(const int* __restrict__ dst, int* __restrict__ chist,
                                             const float* __restrict__ x, unsigned int* __restrict__ xb,
                                             int E, int nbk, int EB2, int n2) {
    __shared__ int lcnt[BK_NODES];
    const int bid = blockIdx.x;
    const int t = threadIdx.x;
    if (bid < EB2) {
        if (t < nbk) lcnt[t] = 0;
        __syncthreads();
        int e0 = bid * 4096;
        #pragma unroll
        for (int j = 0; j < 8; ++j) {
            int e = e0 + j * 512 + t;
            if (e < E) atomicAdd(&lcnt[dst[e] >> BK_SHIFT], 1);
        }
        __syncthreads();
        if (t < nbk && lcnt[t]) atomicAdd(&chist[t], lcnt[t]);
    } else {
        int base = (bid - EB2) * 2048;
        #pragma unroll
        for (int j = 0; j < 4; ++j) {
            int i = base + j * 512 + t;
            if (i < n2) {
                float2 v = ((const float2*)x)[i];
                xb[i] = pack_bf16(v.x, v.y);
            }
        }
    }
}

// ---------------- pass 1: counting sort, 4096 edges/block, local chist scan ----------------
__global__ __launch_bounds__(512) void k_bin(const int* __restrict__ src,
                                             const int* __restrict__ dst,
                                             const int* __restrict__ chist,
                                             int* __restrict__ bcursor0,
                                             int* __restrict__ pairBuf, int E, int nbk) {
    __shared__ int lcnt[BK_NODES];
    __shared__ int lofs[BK_NODES];
    __shared__ int delta[BK_NODES];
    __shared__ int waveSum[8];
    __shared__ int sPack[4096];
    __shared__ unsigned short sBkt[4096];
    const int t = threadIdx.x;
    const int lane = t & 63;
    const int w = t >> 6;
    const int e0 = blockIdx.x * 4096;
    if (t < nbk) lcnt[t] = 0;
    __syncthreads();

    int mySrc[8], myB[8], myDl[8];
    #pragma unroll
    for (int j = 0; j < 8; ++j) {
        int e = e0 + j * 512 + t;
        if (e < E) {
            int sv = src[e], dv = dst[e];
            mySrc[j] = sv; myB[j] = dv >> BK_SHIFT; myDl[j] = dv & (BK_NODES - 1);
            atomicAdd(&lcnt[myB[j]], 1);
        } else myB[j] = -1;
    }
    __syncthreads();

    // wave-shuffle exclusive scan over lcnt, and local scan of chist for base
    int v = (t < nbk) ? lcnt[t] : 0;
    int inc = v;
    #pragma unroll
    for (int off = 1; off < 64; off <<= 1) {
        int n = __shfl_up(inc, off);
        if (lane >= off) inc += n;
    }
    if (lane == 63) waveSum[w] = inc;
    int cv = (t < nbk) ? chist[t] : 0;   // global bucket count
    int cinc = cv;
    #pragma unroll
    for (int off = 1; off < 64; off <<= 1) {
        int n = __shfl_up(cinc, off);
        if (lane >= off) cinc += n;
    }
    __shared__ int cWaveSum[8];
    if (lane == 63) cWaveSum[w] = cinc;
    __syncthreads();
    int wp = 0, cwp = 0;
    #pragma unroll
    for (int i = 0; i < 8; ++i) {
        wp += (i < w) ? waveSum[i] : 0;
        cwp += (i < w) ? cWaveSum[i] : 0;
    }
    int ex = wp + inc - v;         // exclusive prefix of local counts
    int cbase = cwp + cinc - cv;   // global bucket base (exclusive scan of chist)
    if (t < nbk) {
        lofs[t] = ex;
        int gb = cbase + ((v > 0) ? atomicAdd(&bcursor0[t], v) : 0);
        delta[t] = gb - ex;
    }
    __syncthreads();

    #pragma unroll
    for (int j = 0; j < 8; ++j) {
        if (myB[j] >= 0) {
            int p = atomicAdd(&lofs[myB[j]], 1);
            sPack[p] = mySrc[j] | (myDl[j] << 18);   // src < 2^18
            sBkt[p] = (unsigned short)myB[j];
        }
    }
    __syncthreads();
    int total = (E - e0 < 4096) ? (E - e0) : 4096;
    for (int i = t; i < total; i += 512)
        pairBuf[delta[sBkt[i]] + i] = sPack[i];
}

// ---------------- pass 2: per-bucket rowstart/dinv + csr scatter (local chist scan) ----------------
__global__ __launch_bounds__(512) void k_bscatter(const int* __restrict__ pairBuf,
                                                  const int* __restrict__ chist,
                                                  int* __restrict__ rowstart,
                                                  float* __restrict__ dinv,
                                                  int* __restrict__ csr, int N, int E, int nbk) {
    const int b = blockIdx.x;
    const int n0 = b << BK_SHIFT;
    int nn = N - n0; if (nn > BK_NODES) nn = BK_NODES;
    __shared__ int hist[BK_NODES];
    __shared__ int curs[BK_NODES];
    __shared__ int waveSum[8];
    __shared__ int sE0, sE1;
    const int t = threadIdx.x;
    const int lane = t & 63;
    const int w = t >> 6;

    // local exclusive scan of chist -> this bucket's [e0,e1)
    {
        int cv = (t < nbk) ? chist[t] : 0;
        int cinc = cv;
        #pragma unroll
        for (int off = 1; off < 64; off <<= 1) {
            int n = __shfl_up(cinc, off);
            if (lane >= off) cinc += n;
        }
        if (lane == 63) waveSum[w] = cinc;
        if (t < nn) hist[t] = 0;
        __syncthreads();
        int cwp = 0;
        #pragma unroll
        for (int i = 0; i < 8; ++i) cwp += (i < w) ? waveSum[i] : 0;
        if (t == b) { sE0 = cwp + cinc - cv; sE1 = cwp + cinc; }
    }
    __syncthreads();
    const int e0 = sE0, e1 = sE1;

    for (int e = e0 + t; e < e1; e += 512)
        atomicAdd(&hist[pairBuf[e] >> 18], 1);
    __syncthreads();

    int v = (t < nn) ? hist[t] : 0;
    int inc = v;
    #pragma unroll
    for (int off = 1; off < 64; off <<= 1) {
        int n = __shfl_up(inc, off);
        if (lane >= off) inc += n;
    }
    if (lane == 63) waveSum[w] = inc;
    __syncthreads();
    int wp = 0;
    #pragma unroll
    for (int i = 0; i < 8; ++i) wp += (i < w) ? waveSum[i] : 0;
    int ex = wp + inc - v;
    if (t < nn) {
        int r = e0 + ex;
        rowstart[n0 + t] = r;
        curs[t] = r;
        dinv[n0 + t] = rsqrtf((float)(v + 1));
    }
    if (b == gridDim.x - 1 && t == 0) rowstart[N] = E;
    __syncthreads();
    for (int e = e0 + t; e < e1; e += 512) {
        int pk = pairBuf[e];
        int pos = atomicAdd(&curs[pk >> 18], 1);
        csr[pos] = pk & 0x3FFFF;
    }
}

// ---------------- gather1: aggXb = bf16(A_hat x); all-bf16, dwordx4, 8 edges/instr ----------------
__global__ __launch_bounds__(256) void k_gather1(const int* __restrict__ rowstart,
                                                 const int* __restrict__ csr,
                                                 const float* __restrict__ dinv,
                                                 const uint4* __restrict__ xb4,
                                                 unsigned int* __restrict__ outb, int N) {
    const int node = blockIdx.x * 4 + (threadIdx.x >> 6);
    const int l = threadIdx.x & 63;
    if (node >= N) return;
    const int sub = l >> 3;
    const int c = l & 7;
    const int rs = rowstart[node];
    const int re = rowstart[node + 1];

    float acc[8] = {0.f, 0.f, 0.f, 0.f, 0.f, 0.f, 0.f, 0.f};
    for (int base = rs; base < re; base += 64) {
        int idx = base + l;
        int sE = (idx < re) ? csr[idx] : 0;
        float dE = (idx < re) ? dinv[sE] : 0.0f;
        int cnt = re - base; if (cnt > 64) cnt = 64;
        int groups = (cnt + 7) >> 3;
        for (int g = 0; g < groups; ++g) {
            int e = g * 8 + sub;
            int sk = __shfl(sE, e);
            float dk = __shfl(dE, e);
            uint4 u = xb4[(size_t)sk * 8 + c];
            acc[0] += dk * bf_lo(u.x); acc[1] += dk * bf_hi(u.x);
            acc[2] += dk * bf_lo(u.y); acc[3] += dk * bf_hi(u.y);
            acc[4] += dk * bf_lo(u.z); acc[5] += dk * bf_hi(u.z);
            acc[6] += dk * bf_lo(u.w); acc[7] += dk * bf_hi(u.w);
        }
    }
    #pragma unroll
    for (int m = 8; m < 64; m <<= 1)
        #pragma unroll
        for (int i = 0; i < 8; ++i) acc[i] += __shfl_xor(acc[i], m);
    if (sub == 0) {
        float dd = dinv[node];
        float d2 = dd * dd;
        uint4 us = xb4[(size_t)node * 8 + c];   // bf16 self term
        uint4 o;
        o.x = pack_bf16(dd * acc[0] + d2 * bf_lo(us.x), dd * acc[1] + d2 * bf_hi(us.x));
        o.y = pack_bf16(dd * acc[2] + d2 * bf_lo(us.y), dd * acc[3] + d2 * bf_hi(us.y));
        o.z = pack_bf16(dd * acc[4] + d2 * bf_lo(us.z), dd * acc[5] + d2 * bf_hi(us.z));
        o.w = pack_bf16(dd * acc[6] + d2 * bf_lo(us.w), dd * acc[7] + d2 * bf_hi(us.w));
        ((uint4*)outb)[(size_t)node * 8 + c] = o;
    }
}

// ---------------- fused layer1+layer2 via MFMA bf16 ----------------
__global__ __launch_bounds__(256) void k_layer12(const unsigned int* __restrict__ aggXb,
                                                 const float* __restrict__ W1,
                                                 const float* __restrict__ b1,
                                                 const float* __restrict__ W2,
                                                 const float* __restrict__ dinv,
                                                 unsigned int* __restrict__ xs2b, int N) {
    __shared__ unsigned int sA[64 * 36];    // aggX bf16; later C2 out-stage
    __shared__ unsigned int sB[128 * 36];   // W1T bf16 (stride 36); later W2T (stride 68)
    __shared__ unsigned int sC[64 * 68];    // h1 bf16 (stride 68 uints = 136 bf16)
    const int t = threadIdx.x;
    const int w = t >> 6;
    const int l = t & 63;
    const int n16 = l & 15;
    const int quad = l >> 4;
    const int row0 = blockIdx.x * 64;

    for (int i = t; i < 512; i += 256) {
        int r = i >> 3, c = i & 7;
        int row = row0 + r;
        uint4 u = (row < N) ? ((const uint4*)aggXb)[(size_t)row * 8 + c]
                            : make_uint4(0u, 0u, 0u, 0u);
        *(uint4*)&sA[r * 36 + c * 4] = u;
    }
    for (int i = t; i < 4096; i += 256) {
        int kp = i >> 7, n = i & 127;
        float a0 = W1[(size_t)(2 * kp) * 128 + n];
        float a1 = W1[(size_t)(2 * kp + 1) * 128 + n];
        sB[n * 36 + kp] = pack_bf16(a0, a1);
    }
    __syncthreads();

    f32x4 acc[8];
    #pragma unroll
    for (int nt = 0; nt < 8; ++nt) acc[nt] = (f32x4){0.f, 0.f, 0.f, 0.f};
    {
        const int am = w * 16 + n16;
        bf8_t a0 = *(const bf8_t*)&sA[am * 36 + quad * 4];
        bf8_t a1 = *(const bf8_t*)&sA[am * 36 + 16 + quad * 4];
        #pragma unroll
        for (int nt = 0; nt < 8; ++nt) {
            bf8_t b0 = *(const bf8_t*)&sB[(nt * 16 + n16) * 36 + quad * 4];
            bf8_t b1v = *(const bf8_t*)&sB[(nt * 16 + n16) * 36 + 16 + quad * 4];
            acc[nt] = __builtin_amdgcn_mfma_f32_16x16x32_bf16(a0, b0, acc[nt], 0, 0, 0);
            acc[nt] = __builtin_amdgcn_mfma_f32_16x16x32_bf16(a1, b1v, acc[nt], 0, 0, 0);
        }
    }
    __syncthreads();

    {
        unsigned short* sC16 = (unsigned short*)sC;
        #pragma unroll
        for (int nt = 0; nt < 8; ++nt) {
            int col = nt * 16 + n16;
            float bv = b1[col];
            #pragma unroll
            for (int reg = 0; reg < 4; ++reg) {
                int r = w * 16 + quad * 4 + reg;
                sC16[r * 136 + col] = bf16_1(fmaxf(acc[nt][reg] + bv, 0.f));
            }
        }
    }
    for (int i = t; i < 4096; i += 256) {
        int kp = i >> 6, n = i & 63;
        float a0 = W2[(size_t)(2 * kp) * 64 + n];
        float a1 = W2[(size_t)(2 * kp + 1) * 64 + n];
        sB[n * 68 + kp] = pack_bf16(a0, a1);
    }
    __syncthreads();

    f32x4 acc2[4];
    #pragma unroll
    for (int nt = 0; nt < 4; ++nt) acc2[nt] = (f32x4){0.f, 0.f, 0.f, 0.f};
    {
        const int am = w * 16 + n16;
        #pragma unroll
        for (int ks = 0; ks < 4; ++ks) {
            bf8_t a = *(const bf8_t*)&sC[am * 68 + ks * 16 + quad * 4];
            #pragma unroll
            for (int nt = 0; nt < 4; ++nt) {
                bf8_t b = *(const bf8_t*)&sB[(nt * 16 + n16) * 68 + ks * 16 + quad * 4];
                acc2[nt] = __builtin_amdgcn_mfma_f32_16x16x32_bf16(a, b, acc2[nt], 0, 0, 0);
            }
        }
    }

    {
        unsigned short* sA16 = (unsigned short*)sA;
        #pragma unroll
        for (int reg = 0; reg < 4; ++reg) {
            int r = w * 16 + quad * 4 + reg;
            int row = row0 + r;
            float dd = (row < N) ? dinv[row] : 0.f;
            #pragma unroll
            for (int nt = 0; nt < 4; ++nt)
                sA16[r * 72 + nt * 16 + n16] = bf16_1(acc2[nt][reg] * dd);
        }
    }
    __syncthreads();
    for (int i = t; i < 512; i += 256) {
        int r = i >> 3, c = i & 7;
        int row = row0 + r;
        if (row < N)
            ((uint4*)xs2b)[(size_t)row * 8 + c] = *(uint4*)&sA[r * 36 + c * 4];
    }
}

// ---------------- gather_pairs (dwordx4 loads): cB[b] = [h2(u), h2(i)] ----------------
__global__ __launch_bounds__(256) void k_gather_pairs(const int* __restrict__ rowstart,
                                                      const int* __restrict__ csr,
                                                      const float* __restrict__ dinv,
                                                      const uint4* __restrict__ xs2b4,
                                                      const float* __restrict__ b2,
                                                      const int* __restrict__ ui,
                                                      const int* __restrict__ ii,
                                                      float* __restrict__ cB, int B) {
    const int wave = threadIdx.x >> 6;
    const int b = blockIdx.x * 2 + (wave >> 1);
    const int half = wave & 1;
    const int l = threadIdx.x & 63;
    const int sub = l >> 3;
    const int c = l & 7;
    if (b >= B) return;
    const int node = (half == 0) ? (ui[b] - 1) : (N_USERS_C + ii[b] - 1);
    const int rs = rowstart[node];
    const int re = rowstart[node + 1];

    float acc[8] = {0.f, 0.f, 0.f, 0.f, 0.f, 0.f, 0.f, 0.f};
    for (int base = rs; base < re; base += 64) {
        int idx = base + l;
        int sE = (idx < re) ? csr[idx] : 0;
        float vE = (idx < re) ? 1.0f : 0.0f;
        int cnt = re - base; if (cnt > 64) cnt = 64;
        int groups = (cnt + 7) >> 3;
        for (int g = 0; g < groups; ++g) {
            int e = g * 8 + sub;
            int sk = __shfl(sE, e);
            float vk = __shfl(vE, e);
            uint4 u = xs2b4[(size_t)sk * 8 + c];
            acc[0] += vk * bf_lo(u.x); acc[1] += vk * bf_hi(u.x);
            acc[2] += vk * bf_lo(u.y); acc[3] += vk * bf_hi(u.y);
            acc[4] += vk * bf_lo(u.z); acc[5] += vk * bf_hi(u.z);
            acc[6] += vk * bf_lo(u.w); acc[7] += vk * bf_hi(u.w);
        }
    }
    #pragma unroll
    for (int m = 8; m < 64; m <<= 1)
        #pragma unroll
        for (int i = 0; i < 8; ++i) acc[i] += __shfl_xor(acc[i], m);
    if (sub == 0) {
        float dd = dinv[node];
        uint4 us = xs2b4[(size_t)node * 8 + c];
        float4 s0, s1;
        s0.x = bf_lo(us.x); s0.y = bf_hi(us.x); s0.z = bf_lo(us.y); s0.w = bf_hi(us.y);
        s1.x = bf_lo(us.z); s1.y = bf_hi(us.z); s1.z = bf_lo(us.w); s1.w = bf_hi(us.w);
        float4 bb0 = ((const float4*)b2)[c * 2];
        float4 bb1 = ((const float4*)b2)[c * 2 + 1];
        float4 o0, o1;
        o0.x = dd * (acc[0] + s0.x) + bb0.x;
        o0.y = dd * (acc[1] + s0.y) + bb0.y;
        o0.z = dd * (acc[2] + s0.z) + bb0.z;
        o0.w = dd * (acc[3] + s0.w) + bb0.w;
        o1.x = dd * (acc[4] + s1.x) + bb1.x;
        o1.y = dd * (acc[5] + s1.y) + bb1.y;
        o1.z = dd * (acc[6] + s1.z) + bb1.z;
        o1.w = dd * (acc[7] + s1.w) + bb1.w;
        ((float4*)cB)[(size_t)b * 32 + half * 16 + c * 2] = o0;
        ((float4*)cB)[(size_t)b * 32 + half * 16 + c * 2 + 1] = o1;
    }
}

// ---------------- fused MLP: 32 rows/block ----------------
__global__ __launch_bounds__(256) void k_mlp(const float* __restrict__ cB,
                                             const float* __restrict__ fcW1, const float* __restrict__ fcb1,
                                             const float* __restrict__ g1,   const float* __restrict__ be1,
                                             const float* __restrict__ fcW2, const float* __restrict__ fcb2,
                                             const float* __restrict__ g2,   const float* __restrict__ be2,
                                             const float* __restrict__ fcW3, const float* __restrict__ fcb3,
                                             float* __restrict__ out) {
    __shared__ float sIn[32 * 128];
    __shared__ float sW[64 * 128];
    const int t = threadIdx.x;
    const int row0 = blockIdx.x * 32;
    const int rg = t >> 4;
    const int cg = t & 15;

    for (int i = t; i < 1024; i += 256) {
        int r = i >> 5, c4 = i & 31;
        *(float4*)&sIn[r * 128 + c4 * 4] = *(const float4*)&cB[(size_t)(row0 + r) * 128 + c4 * 4];
    }

    float acc1[2][8];
    {
        float4 b01 = *(const float4*)&fcb1[cg * 8];
        float4 b23 = *(const float4*)&fcb1[cg * 8 + 4];
        #pragma unroll
        for (int jj = 0; jj < 2; ++jj) {
            acc1[jj][0] = b01.x; acc1[jj][1] = b01.y; acc1[jj][2] = b01.z; acc1[jj][3] = b01.w;
            acc1[jj][4] = b23.x; acc1[jj][5] = b23.y; acc1[jj][6] = b23.z; acc1[jj][7] = b23.w;
        }
    }
    for (int s = 0; s < 2; ++s) {
        __syncthreads();
        for (int i = t; i < 2048; i += 256) {
            int k = i >> 5, c4 = i & 31;
            *(float4*)&sW[k * 128 + c4 * 4] = *(const float4*)&fcW1[(size_t)(64 * s + k) * 128 + c4 * 4];
        }
        __syncthreads();
        for (int k0 = 0; k0 < 64; k0 += 4) {
            float4 a[2];
            #pragma unroll
            for (int jj = 0; jj < 2; ++jj)
                a[jj] = *(const float4*)&sIn[(rg * 2 + jj) * 128 + 64 * s + k0];
            #pragma unroll
            for (int kk = 0; kk < 4; ++kk) {
                float4 w0 = *(const float4*)&sW[(k0 + kk) * 128 + cg * 8];
                float4 w1 = *(const float4*)&sW[(k0 + kk) * 128 + cg * 8 + 4];
                #pragma unroll
                for (int jj = 0; jj < 2; ++jj) {
                    float f = ((const float*)&a[jj])[kk];
                    acc1[jj][0] += f * w0.x; acc1[jj][1] += f * w0.y;
                    acc1[jj][2] += f * w0.z; acc1[jj][3] += f * w0.w;
                    acc1[jj][4] += f * w1.x; acc1[jj][5] += f * w1.y;
                    acc1[jj][6] += f * w1.z; acc1[jj][7] += f * w1.w;
                }
            }
        }
    }
    __syncthreads();

    {
        float4 g01 = *(const float4*)&g1[cg * 8];
        float4 g23 = *(const float4*)&g1[cg * 8 + 4];
        float4 e01 = *(const float4*)&be1[cg * 8];
        float4 e23 = *(const float4*)&be1[cg * 8 + 4];
        float gv[8] = {g01.x, g01.y, g01.z, g01.w, g23.x, g23.y, g23.z, g23.w};
        float ev[8] = {e01.x, e01.y, e01.z, e01.w, e23.x, e23.y, e23.z, e23.w};
        #pragma unroll
        for (int jj = 0; jj < 2; ++jj) {
            float s_ = 0.f, ss = 0.f;
            #pragma unroll
            for (int c = 0; c < 8; ++c) { float v = acc1[jj][c]; s_ += v; ss += v * v; }
            #pragma unroll
            for (int m = 1; m < 16; m <<= 1) { s_ += __shfl_xor(s_, m); ss += __shfl_xor(ss, m); }
            float mu = s_ * (1.0f / 128.0f);
            float var = ss * (1.0f / 128.0f) - mu * mu;
            float rs = rsqrtf(var + 1e-5f);
            #pragma unroll
            for (int c = 0; c < 8; ++c) {
                float z = (acc1[jj][c] - mu) * rs * gv[c] + ev[c];
                sIn[(rg * 2 + jj) * 128 + cg * 8 + c] = fmaxf(z, 0.f);
            }
        }
    }
    __syncthreads();

    for (int i = t; i < 2048; i += 256) {
        int k = i >> 4, c4 = i & 15;
        *(float4*)&sW[k * 64 + c4 * 4] = *(const float4*)&fcW2[(size_t)k * 64 + c4 * 4];
    }
    float acc2[2][4];
    {
        float4 bv = *(const float4*)&fcb2[cg * 4];
        #pragma unroll
        for (int jj = 0; jj < 2; ++jj) {
            acc2[jj][0] = bv.x; acc2[jj][1] = bv.y; acc2[jj][2] = bv.z; acc2[jj][3] = bv.w;
        }
    }
    __syncthreads();
    for (int k0 = 0; k0 < 128; k0 += 4) {
        float4 a[2], w[4];
        #pragma unroll
        for (int jj = 0; jj < 2; ++jj) a[jj] = *(const float4*)&sIn[(rg * 2 + jj) * 128 + k0];
        #pragma unroll
        for (int kk = 0; kk < 4; ++kk) w[kk] = *(const float4*)&sW[(k0 + kk) * 64 + cg * 4];
        #pragma unroll
        for (int jj = 0; jj < 2; ++jj) {
            const float* aj = (const float*)&a[jj];
            #pragma unroll
            for (int kk = 0; kk < 4; ++kk) {
                float f = aj[kk];
                acc2[jj][0] += f * w[kk].x; acc2[jj][1] += f * w[kk].y;
                acc2[jj][2] += f * w[kk].z; acc2[jj][3] += f * w[kk].w;
            }
        }
    }

    {
        float4 gv4 = *(const float4*)&g2[cg * 4];
        float4 ev4 = *(const float4*)&be2[cg * 4];
        float4 w34 = *(const float4*)&fcW3[cg * 4];
        float gv[4] = {gv4.x, gv4.y, gv4.z, gv4.w};
        float ev[4] = {ev4.x, ev4.y, ev4.z, ev4.w};
        float wv[4] = {w34.x, w34.y, w34.z, w34.w};
        float b3 = fcb3[0];
        #pragma unroll
        for (int jj = 0; jj < 2; ++jj) {
            float s_ = 0.f, ss = 0.f;
            #pragma unroll
            for (int c = 0; c < 4; ++c) { float v = acc2[jj][c]; s_ += v; ss += v * v; }
            #pragma unroll
            for (int m = 1; m < 16; m <<= 1) { s_ += __shfl_xor(s_, m); ss += __shfl_xor(ss, m); }
            float mu = s_ * (1.0f / 64.0f);
            float var = ss * (1.0f / 64.0f) - mu * mu;
            float rs = rsqrtf(var + 1e-5f);
            float p = 0.f;
            #pragma unroll
            for (int c = 0; c < 4; ++c) {
                float z = fmaxf((acc2[jj][c] - mu) * rs * gv[c] + ev[c], 0.f);
                p += z * wv[c];
            }
            #pragma unroll
            for (int m = 1; m < 16; m <<= 1) p += __shfl_xor(p, m);
            if (cg == 0) out[row0 + rg * 2 + jj] = 1.0f / (1.0f + expf(-(p + b3)));
        }
    }
}

extern "C" void kernel_launch(void* const* d_in, const int* in_sizes, int n_in,
                              void* d_out, int out_size, void* d_ws, size_t ws_size,
                              hipStream_t stream) {
    const float* x    = (const float*)d_in[0];
    const int*   src  = (const int*)d_in[1];
    const int*   dst  = (const int*)d_in[2];
    const int*   ui   = (const int*)d_in[3];
    const int*   ii   = (const int*)d_in[4];
    const float* W1   = (const float*)d_in[5];
    const float* b1   = (const float*)d_in[6];
    const float* W2   = (const float*)d_in[7];
    const float* b2   = (const float*)d_in[8];
    const float* fcW1 = (const float*)d_in[9];
    const float* fcb1 = (const float*)d_in[10];
    const float* g1   = (const float*)d_in[11];
    const float* be1  = (const float*)d_in[12];
    const float* fcW2 = (const float*)d_in[13];
    const float* fcb2 = (const float*)d_in[14];
    const float* g2   = (const float*)d_in[15];
    const float* be2  = (const float*)d_in[16];
    const float* fcW3 = (const float*)d_in[17];
    const float* fcb3 = (const float*)d_in[18];
    float* out = (float*)d_out;

    const int N = in_sizes[0] / 64;          // 150000
    const int E = in_sizes[1];               // 2400000
    const int B = in_sizes[3];               // 16384
    const int NBK = (N + BK_NODES - 1) >> BK_SHIFT;   // 293
    const int EB2 = (E + 4095) / 4096;       // 586 (hist + bin blocks)
    const int n2 = N * 32;
    const int XB = (n2 + 2047) / 2048;

    // ---- workspace layout (~77 MB) ----
    float* ws   = (float*)d_ws;
    float* dinv = ws;                                   // N
    int* rowstart = (int*)(dinv + N);                   // N+1
    int* csr      = rowstart + (N + 1);                 // E
    unsigned int* xb = (unsigned int*)(csr + E);        // N*32 (bf16 x)
    unsigned int* bufU = xb + (size_t)N * 32;           // N*32: CSR scratch, then aggXb
    unsigned int* xs2b = bufU + (size_t)N * 32;         // N*32 (bf16 xs2)
    float* cB = (float*)(xs2b + (size_t)N * 32);        // B*128 f32
    int* pairBuf = (int*)bufU;                          // E
    int* chist   = pairBuf + E;                         // 512
    int* bcursor = chist + 512;                         // 512 (adjacent: one memset)
    unsigned int* aggXb = bufU;                         // N*32 (bf16 aggX)

    // ---- CSR build + bf16 conversion ----
    hipMemsetAsync(chist, 0, 1024 * sizeof(int), stream);   // chist + bcursor
    k_pre<<<EB2 + XB, 512, 0, stream>>>(dst, chist, x, xb, E, NBK, EB2, n2);
    k_bin<<<EB2, 512, 0, stream>>>(src, dst, chist, bcursor, pairBuf, E, NBK);
    k_bscatter<<<NBK, 512, 0, stream>>>(pairBuf, chist, rowstart, dinv, csr, N, E, NBK);

    // ---- layer 1 gather ----
    k_gather1<<<(N + 3) / 4, 256, 0, stream>>>(rowstart, csr, dinv, (const uint4*)xb, aggXb, N);

    // ---- fused layer1+layer2 GEMMs (MFMA bf16) ----
    k_layer12<<<(N + 63) / 64, 256, 0, stream>>>(aggXb, W1, b1, W2, dinv, xs2b, N);

    // ---- pruned gather2 + concat ----
    k_gather_pairs<<<(B + 1) / 2, 256, 0, stream>>>(rowstart, csr, dinv, (const uint4*)xs2b,
                                                    b2, ui, ii, cB, B);

    // ---- fused MLP ----
    k_mlp<<<B / 32, 256, 0, stream>>>(cB, fcW1, fcb1, g1, be1,
                                      fcW2, fcb2, g2, be2, fcW3, fcb3, out);
}